// Round 3
// baseline (245.715 us; speedup 1.0000x reference)
//
#include <hip/hip_runtime.h>

#define HW 2304          // n = 48*48
#define CH 64            // DIM
#define NQT 36           // HW/64 q-tiles of 64
#define NCHUNK 9         // kv chunks of 256

// ---------------------------------------------------------------------------
// K1: transpose-load + LayerNorm + two projections per branch.
// grid (72, 2): x = b*36+qtile, y = branch (0: x->x1,x2 via w_se*, 1: y->y1,y2 via w_sa*)
// block 256 = 64 q * 4 head-groups. Outputs [b][h][n][16], coalesced float4.
// ---------------------------------------------------------------------------
__global__ __launch_bounds__(256) void k_ln_proj(
    const float* __restrict__ x, const float* __restrict__ y,
    const float* __restrict__ g, const float* __restrict__ bb,
    const float* __restrict__ wsa1, const float* __restrict__ wsa2,
    const float* __restrict__ wse1, const float* __restrict__ wse2,
    float* __restrict__ x1, float* __restrict__ x2,
    float* __restrict__ y1, float* __restrict__ y2)
{
    __shared__ float wA[64][64];
    __shared__ float wB[64][64];
    __shared__ float gs[64], bs[64];
    const int branch = blockIdx.y;
    const float* in = branch ? y : x;
    const float* pA = branch ? wsa1 : wse1;
    const float* pB = branch ? wsa2 : wse2;
    float* o1 = branch ? y1 : x1;
    float* o2 = branch ? y2 : x2;
    const int b  = blockIdx.x / NQT;
    const int qt = blockIdx.x % NQT;
    const int tid = threadIdx.x;
    for (int t = tid; t < 4096; t += 256) { wA[t >> 6][t & 63] = pA[t]; wB[t >> 6][t & 63] = pB[t]; }
    if (tid < 64) { gs[tid] = g[tid]; bs[tid] = bb[tid]; }
    __syncthreads();
    const int qs = tid & 63;
    const int h  = tid >> 6;          // uniform per wave
    const int q  = qt * 64 + qs;
    const float* src = in + (size_t)b * CH * HW + q;
    float v[64];
    float m = 0.f;
    #pragma unroll
    for (int c = 0; c < 64; ++c) { v[c] = src[(size_t)c * HW]; m += v[c]; }
    m *= (1.f / 64.f);
    float var = 0.f;
    #pragma unroll
    for (int c = 0; c < 64; ++c) { float d = v[c] - m; var += d * d; }
    const float r = rsqrtf(var * (1.f / 64.f) + 1e-5f);
    #pragma unroll
    for (int c = 0; c < 64; ++c) v[c] = (v[c] - m) * r * gs[c] + bs[c];
    float a1v[16], a2v[16];
    #pragma unroll
    for (int dd = 0; dd < 16; ++dd) {
        const int jj = h * 16 + dd;
        float a1 = 0.f, a2 = 0.f;
        #pragma unroll
        for (int c = 0; c < 64; ++c) { a1 += v[c] * wA[c][jj]; a2 += v[c] * wB[c][jj]; }
        a1v[dd] = a1; a2v[dd] = a2;
    }
    const size_t o = ((((size_t)b * 4 + h) * HW) + q) * 16;
    #pragma unroll
    for (int i = 0; i < 4; ++i) {
        ((float4*)(o1 + o))[i] = ((const float4*)a1v)[i];
        ((float4*)(o2 + o))[i] = ((const float4*)a2v)[i];
    }
}

// ---------------------------------------------------------------------------
// K2: channel attention map secm[bh][16][16] = softmax_j( (x1^T x2) * 0.25/144 )
// 8 blocks (one per b,h), 256 threads = (i,j) pairs, LDS-chunked over n.
// ---------------------------------------------------------------------------
__global__ __launch_bounds__(256) void k_secm(
    const float* __restrict__ x1, const float* __restrict__ x2, float* __restrict__ secm)
{
    __shared__ float c1[256][16];
    __shared__ float c2[256][16];
    __shared__ float S[256];
    const int bh = blockIdx.x;
    const int tid = threadIdx.x;
    const int i = tid >> 4, j = tid & 15;
    const float* p1 = x1 + (size_t)bh * HW * 16;
    const float* p2 = x2 + (size_t)bh * HW * 16;
    float acc = 0.f;
    for (int ch = 0; ch < NCHUNK; ++ch) {
        __syncthreads();
        const float4* s1 = (const float4*)(p1 + (size_t)ch * 256 * 16);
        const float4* s2 = (const float4*)(p2 + (size_t)ch * 256 * 16);
        for (int t = tid; t < 1024; t += 256) { ((float4*)c1)[t] = s1[t]; ((float4*)c2)[t] = s2[t]; }
        __syncthreads();
        #pragma unroll 8
        for (int nn = 0; nn < 256; ++nn) acc += c1[nn][i] * c2[nn][j];
    }
    acc *= (0.25f / 144.f);
    S[tid] = acc;
    __syncthreads();
    float mx = -1e30f;
    #pragma unroll
    for (int jj = 0; jj < 16; ++jj) mx = fmaxf(mx, S[i * 16 + jj]);
    float sum = 0.f;
    #pragma unroll
    for (int jj = 0; jj < 16; ++jj) sum += __expf(S[i * 16 + jj] - mx);
    secm[(size_t)bh * 256 + tid] = __expf(acc - mx) / sum;
}

// ---------------------------------------------------------------------------
// K3: spatial attention partials (no max-subtraction: logits are tiny, softmax
// is shift-invariant, so partial (acc, l) are plain sums -> trivially mergeable).
// grid (72, 9): x = bh*9+qtile(256 q), y = kv-chunk(256 j). block 256 = 1 q/thread.
// ---------------------------------------------------------------------------
__global__ __launch_bounds__(256) void k_attn_partial(
    const float* __restrict__ y1, const float* __restrict__ y2, const float* __restrict__ x1,
    float* __restrict__ pacc, float* __restrict__ pl)
{
    __shared__ float kt[256][16];
    __shared__ float vt[256][16];
    const int bh = blockIdx.x / NCHUNK;
    const int qt = blockIdx.x % NCHUNK;
    const int ch = blockIdx.y;
    const int tid = threadIdx.x;
    const float4* pk = (const float4*)(y2 + ((size_t)bh * HW + ch * 256) * 16);
    const float4* pv = (const float4*)(x1 + ((size_t)bh * HW + ch * 256) * 16);
    for (int t = tid; t < 1024; t += 256) { ((float4*)kt)[t] = pk[t]; ((float4*)vt)[t] = pv[t]; }
    const int q = qt * 256 + tid;
    float qr[16];
    const float4* pq = (const float4*)(y1 + ((size_t)bh * HW + q) * 16);
    #pragma unroll
    for (int i = 0; i < 4; ++i) ((float4*)qr)[i] = pq[i];
    // fold scale*log2(e) into q so inner loop uses native exp2
    #pragma unroll
    for (int d = 0; d < 16; ++d) qr[d] *= 0.25f * 1.44269504088896340736f;
    __syncthreads();
    float acc[16];
    #pragma unroll
    for (int d = 0; d < 16; ++d) acc[d] = 0.f;
    float l = 0.f;
    #pragma unroll 2
    for (int jj = 0; jj < 256; ++jj) {
        float s = 0.f;
        #pragma unroll
        for (int d = 0; d < 16; ++d) s += qr[d] * kt[jj][d];
        const float e = exp2f(s);
        l += e;
        #pragma unroll
        for (int d = 0; d < 16; ++d) acc[d] += e * vt[jj][d];
    }
    const size_t pb = ((size_t)bh * NCHUNK + ch) * HW + q;
    float* pa = pacc + pb * 16;
    #pragma unroll
    for (int i = 0; i < 4; ++i) ((float4*)pa)[i] = ((const float4*)acc)[i];
    pl[pb] = l;
}

// ---------------------------------------------------------------------------
// K3b: merge partials, normalize, apply channel gate out2 = y1 @ secm, write
// gated out[b][q][h*16+d]. grid 72 = bh*9+qtile, block 256 = 1 q/thread.
// ---------------------------------------------------------------------------
__global__ __launch_bounds__(256) void k_attn_combine(
    const float* __restrict__ pacc, const float* __restrict__ pl,
    const float* __restrict__ secm, const float* __restrict__ y1,
    float* __restrict__ outa)
{
    __shared__ float sm[16][16];
    const int bh = blockIdx.x / NCHUNK;
    const int qt = blockIdx.x % NCHUNK;
    const int tid = threadIdx.x;
    sm[tid >> 4][tid & 15] = secm[(size_t)bh * 256 + tid];
    const int q = qt * 256 + tid;
    float qr[16];
    const float4* pq = (const float4*)(y1 + ((size_t)bh * HW + q) * 16);
    #pragma unroll
    for (int i = 0; i < 4; ++i) ((float4*)qr)[i] = pq[i];
    float acc[16];
    #pragma unroll
    for (int d = 0; d < 16; ++d) acc[d] = 0.f;
    float l = 0.f;
    for (int ch = 0; ch < NCHUNK; ++ch) {
        const size_t pb = ((size_t)bh * NCHUNK + ch) * HW + q;
        const float4* pa = (const float4*)(pacc + pb * 16);
        #pragma unroll
        for (int i = 0; i < 4; ++i) {
            const float4 t = pa[i];
            acc[i * 4 + 0] += t.x; acc[i * 4 + 1] += t.y;
            acc[i * 4 + 2] += t.z; acc[i * 4 + 3] += t.w;
        }
        l += pl[pb];
    }
    __syncthreads();
    const int b = bh >> 2, h = bh & 3;
    const float invl = 1.f / l;
    float res[16];
    #pragma unroll
    for (int d = 0; d < 16; ++d) {
        float o2 = 0.f;
        #pragma unroll
        for (int i = 0; i < 16; ++i) o2 += qr[i] * sm[i][d];
        res[d] = acc[d] * invl * o2;
    }
    float* o = outa + ((size_t)b * HW + q) * 64 + h * 16;
    #pragma unroll
    for (int i = 0; i < 4; ++i) ((float4*)o)[i] = ((const float4*)res)[i];
}

// ---------------------------------------------------------------------------
// K4: attention out-proj + residual: xt2[b][q][c] = x^T + outa @ w_out + b_out
// grid 72 (b*36+qtile of 64 q), block 256 = 64 q * 4 c-groups of 16.
// ---------------------------------------------------------------------------
__global__ __launch_bounds__(256) void k_outproj(
    const float* __restrict__ outa, const float* __restrict__ x,
    const float* __restrict__ w_out, const float* __restrict__ b_out,
    float* __restrict__ xt2)
{
    __shared__ float ws[64][64];
    __shared__ float rows[64][65];   // +1 pad: kills 32-way bank conflict on rows[qs][k]
    const int b  = blockIdx.x / NQT;
    const int qt = blockIdx.x % NQT;
    const int tid = threadIdx.x;
    for (int t = tid; t < 4096; t += 256) ws[t >> 6][t & 63] = w_out[t];
    const float* rsrc = outa + ((size_t)b * HW + qt * 64) * 64;
    for (int t = tid; t < 4096; t += 256) rows[t >> 6][t & 63] = rsrc[t];
    __syncthreads();
    const int qs = tid & 63;
    const int grp = tid >> 6;        // uniform per wave
    const int q = qt * 64 + qs;
    float res[16];
    #pragma unroll 4
    for (int cc = 0; cc < 16; ++cc) {
        const int c = grp * 16 + cc;
        float a = b_out[c];
        #pragma unroll
        for (int k = 0; k < 64; ++k) a += rows[qs][k] * ws[k][c];
        a += x[(size_t)b * CH * HW + (size_t)c * HW + q];
        res[cc] = a;
    }
    float* o = xt2 + ((size_t)b * HW + q) * 64 + grp * 16;
    #pragma unroll
    for (int i = 0; i < 4; ++i) ((float4*)o)[i] = ((const float4*)res)[i];
}

// ---------------------------------------------------------------------------
// K5a: LN2 + MLP layer 1 + LeakyReLU. 8 rows per block (amortizes the 64 KB w1
// read 8x; 1 row/block would cost ~295 MB of L2 traffic). block 256 = hid cols.
// ---------------------------------------------------------------------------
__global__ __launch_bounds__(256) void k_mlp1(
    const float* __restrict__ xt2, const float* __restrict__ g2, const float* __restrict__ b2v,
    const float* __restrict__ w1, const float* __restrict__ b1,
    float* __restrict__ hid)
{
    __shared__ float raw[8][64];
    __shared__ float rn[8][64];
    __shared__ float mv[8][2];
    const int r0 = blockIdx.x * 8;
    const int tid = threadIdx.x;
    const float* src = xt2 + (size_t)r0 * 64;
    for (int t = tid; t < 512; t += 256) raw[t >> 6][t & 63] = src[t];
    __syncthreads();
    if (tid < 8) {
        float m = 0.f;
        #pragma unroll
        for (int c = 0; c < 64; ++c) m += raw[tid][c];
        m *= (1.f / 64.f);
        float var = 0.f;
        #pragma unroll
        for (int c = 0; c < 64; ++c) { float d = raw[tid][c] - m; var += d * d; }
        mv[tid][0] = m;
        mv[tid][1] = rsqrtf(var * (1.f / 64.f) + 1e-5f);
    }
    __syncthreads();
    for (int t = tid; t < 512; t += 256) {
        const int rr = t >> 6, c = t & 63;
        rn[rr][c] = (raw[rr][c] - mv[rr][0]) * mv[rr][1] * g2[c] + b2v[c];
    }
    __syncthreads();
    float acc[8];
    #pragma unroll
    for (int rr = 0; rr < 8; ++rr) acc[rr] = 0.f;
    for (int c = 0; c < 64; ++c) {
        const float wv = w1[(size_t)c * 256 + tid];
        #pragma unroll
        for (int rr = 0; rr < 8; ++rr) acc[rr] += rn[rr][c] * wv;
    }
    const float bv = b1[tid];
    #pragma unroll
    for (int rr = 0; rr < 8; ++rr) {
        const float a = acc[rr] + bv;
        hid[(size_t)(r0 + rr) * 256 + tid] = fmaxf(a, 0.01f * a);
    }
}

// ---------------------------------------------------------------------------
// K5b: MLP layer 2 + residual + transposed (B,C,H,W) output write.
// grid 144 (b*72+qtile of 32 q), block 256 = 32 q * 8 c-groups of 8.
// ---------------------------------------------------------------------------
__global__ __launch_bounds__(256) void k_mlp2(
    const float* __restrict__ hid, const float* __restrict__ xt2,
    const float* __restrict__ w2, const float* __restrict__ b2,
    float* __restrict__ out)
{
    __shared__ float hl[256][33];   // [j][q], +1 pad row stride -> conflict-free
    __shared__ float w2s[256][64];
    const int b  = blockIdx.x / 72;
    const int qt = blockIdx.x % 72;
    const int tid = threadIdx.x;
    for (int t = tid; t < 16384; t += 256) w2s[t >> 6][t & 63] = w2[t];
    const float* hsrc = hid + ((size_t)b * HW + qt * 32) * 256;
    for (int t = tid; t < 8192; t += 256) hl[t & 255][t >> 8] = hsrc[t];
    __syncthreads();
    const int qs = tid & 31;
    const int cg = tid >> 5;        // 0..7
    const int q = qt * 32 + qs;
    float accv[8];
    #pragma unroll
    for (int cc = 0; cc < 8; ++cc) {
        const int c = cg * 8 + cc;
        accv[cc] = b2[c] + xt2[((size_t)b * HW + q) * 64 + c];
    }
    #pragma unroll 4
    for (int j = 0; j < 256; ++j) {
        const float hv = hl[j][qs];
        #pragma unroll
        for (int cc = 0; cc < 8; ++cc) accv[cc] += hv * w2s[j][cg * 8 + cc];
    }
    #pragma unroll
    for (int cc = 0; cc < 8; ++cc) {
        const int c = cg * 8 + cc;
        out[(size_t)b * CH * HW + (size_t)c * HW + q] = accv[cc];
    }
}

extern "C" void kernel_launch(void* const* d_in, const int* in_sizes, int n_in,
                              void* d_out, int out_size, void* d_ws, size_t ws_size,
                              hipStream_t stream)
{
    (void)in_sizes; (void)n_in; (void)out_size; (void)ws_size;
    const float* x     = (const float*)d_in[0];
    const float* y     = (const float*)d_in[1];
    const float* ln1_g = (const float*)d_in[2];
    const float* ln1_b = (const float*)d_in[3];
    const float* w_sa1 = (const float*)d_in[4];
    const float* w_sa2 = (const float*)d_in[5];
    const float* w_se1 = (const float*)d_in[6];
    const float* w_se2 = (const float*)d_in[7];
    const float* w_out = (const float*)d_in[8];
    const float* b_out = (const float*)d_in[9];
    const float* ln2_g = (const float*)d_in[10];
    const float* ln2_b = (const float*)d_in[11];
    const float* w1    = (const float*)d_in[12];
    const float* b1    = (const float*)d_in[13];
    const float* w2    = (const float*)d_in[14];
    const float* b2    = (const float*)d_in[15];
    float* out = (float*)d_out;

    float* ws = (float*)d_ws;
    const size_t NP = 2ull * 4 * HW * 16;           // 294912 per projected tensor
    float* x1   = ws;  ws += NP;
    float* x2   = ws;  ws += NP;
    float* y1   = ws;  ws += NP;
    float* y2   = ws;  ws += NP;
    float* secm = ws;  ws += 2048;
    float* pacc = ws;  ws += 8ull * NCHUNK * HW * 16;   // 10.6 MB
    float* pl   = ws;  ws += 8ull * NCHUNK * HW;
    float* outa = ws;  ws += NP;
    float* xt2  = ws;  ws += NP;
    float* hid  = ws;  ws += 2ull * HW * 256;
    // total ~22 MB of d_ws

    k_ln_proj<<<dim3(2 * NQT, 2), 256, 0, stream>>>(x, y, ln1_g, ln1_b,
                                                    w_sa1, w_sa2, w_se1, w_se2,
                                                    x1, x2, y1, y2);
    k_secm<<<8, 256, 0, stream>>>(x1, x2, secm);
    k_attn_partial<<<dim3(8 * NCHUNK, NCHUNK), 256, 0, stream>>>(y1, y2, x1, pacc, pl);
    k_attn_combine<<<8 * NCHUNK, 256, 0, stream>>>(pacc, pl, secm, y1, outa);
    k_outproj<<<2 * NQT, 256, 0, stream>>>(outa, x, w_out, b_out, xt2);
    k_mlp1<<<2 * HW / 8, 256, 0, stream>>>(xt2, ln2_g, ln2_b, w1, b1, hid);
    k_mlp2<<<144, 256, 0, stream>>>(hid, xt2, w2, b2, out);
}

// Round 4
// 185.984 us; speedup vs baseline: 1.3212x; 1.3212x over previous
//
#include <hip/hip_runtime.h>

#define HW 2304          // n = 48*48
#define CH 64            // DIM
#define NQT 36           // HW/64 q-tiles of 64
#define NKCH 9           // k chunks of 256

typedef __attribute__((ext_vector_type(8))) short bf16x8;
typedef __attribute__((ext_vector_type(4))) float f32x4;

#define QSCL (0.25f * 1.44269504088896340736f)   // attn scale * log2(e), folded into Qbf

static __device__ __forceinline__ unsigned short f2bf(float f) {
    union { float f; unsigned u; } v; v.f = f;
    unsigned r = v.u + 0x7FFFu + ((v.u >> 16) & 1u);   // RNE
    return (unsigned short)(r >> 16);
}

// ---------------------------------------------------------------------------
// K1: transpose-load + LayerNorm + two projections per branch.
// branch 0 (x): x1f, x2f (f32, for secm; x1f also = V f32 unused downstream),
//               vtbf = V^T bf16 [bh][16][HW]
// branch 1 (y): y1f (f32, gate), qbf = y1*QSCL bf16 [bh][n][16], kbf = y2 bf16
// ---------------------------------------------------------------------------
__global__ __launch_bounds__(256) void k_ln_proj(
    const float* __restrict__ x, const float* __restrict__ y,
    const float* __restrict__ g, const float* __restrict__ bb,
    const float* __restrict__ wsa1, const float* __restrict__ wsa2,
    const float* __restrict__ wse1, const float* __restrict__ wse2,
    float* __restrict__ x1f, float* __restrict__ x2f, float* __restrict__ y1f,
    unsigned short* __restrict__ qbf, unsigned short* __restrict__ kbf,
    unsigned short* __restrict__ vtbf)
{
    __shared__ float wA[64][64];
    __shared__ float wB[64][64];
    __shared__ float gs[64], bs[64];
    const int branch = blockIdx.y;
    const float* in = branch ? y : x;
    const float* pA = branch ? wsa1 : wse1;
    const float* pB = branch ? wsa2 : wse2;
    const int b  = blockIdx.x / NQT;
    const int qt = blockIdx.x % NQT;
    const int tid = threadIdx.x;
    for (int t = tid; t < 4096; t += 256) { wA[t >> 6][t & 63] = pA[t]; wB[t >> 6][t & 63] = pB[t]; }
    if (tid < 64) { gs[tid] = g[tid]; bs[tid] = bb[tid]; }
    __syncthreads();
    const int qs = tid & 63;
    const int h  = tid >> 6;          // uniform per wave
    const int q  = qt * 64 + qs;
    const float* src = in + (size_t)b * CH * HW + q;
    float v[64];
    float m = 0.f;
    #pragma unroll
    for (int c = 0; c < 64; ++c) { v[c] = src[(size_t)c * HW]; m += v[c]; }
    m *= (1.f / 64.f);
    float var = 0.f;
    #pragma unroll
    for (int c = 0; c < 64; ++c) { float d = v[c] - m; var += d * d; }
    const float r = rsqrtf(var * (1.f / 64.f) + 1e-5f);
    #pragma unroll
    for (int c = 0; c < 64; ++c) v[c] = (v[c] - m) * r * gs[c] + bs[c];
    float a1v[16], a2v[16];
    #pragma unroll
    for (int dd = 0; dd < 16; ++dd) {
        const int jj = h * 16 + dd;
        float a1 = 0.f, a2 = 0.f;
        #pragma unroll
        for (int c = 0; c < 64; ++c) { a1 += v[c] * wA[c][jj]; a2 += v[c] * wB[c][jj]; }
        a1v[dd] = a1; a2v[dd] = a2;
    }
    const int bh = b * 4 + h;
    const size_t o = ((size_t)bh * HW + q) * 16;
    if (branch == 0) {
        #pragma unroll
        for (int i = 0; i < 4; ++i) {
            ((float4*)(x1f + o))[i] = ((const float4*)a1v)[i];
            ((float4*)(x2f + o))[i] = ((const float4*)a2v)[i];
        }
        #pragma unroll
        for (int dd = 0; dd < 16; ++dd)
            vtbf[((size_t)bh * 16 + dd) * HW + q] = f2bf(a1v[dd]);
    } else {
        #pragma unroll
        for (int i = 0; i < 4; ++i) ((float4*)(y1f + o))[i] = ((const float4*)a1v)[i];
        unsigned uq[8], uk[8];
        #pragma unroll
        for (int p = 0; p < 8; ++p) {
            uq[p] = (unsigned)f2bf(a1v[2*p] * QSCL) | ((unsigned)f2bf(a1v[2*p+1] * QSCL) << 16);
            uk[p] = (unsigned)f2bf(a2v[2*p]) | ((unsigned)f2bf(a2v[2*p+1]) << 16);
        }
        ((uint4*)(qbf + o))[0] = *(uint4*)&uq[0];
        ((uint4*)(qbf + o))[1] = *(uint4*)&uq[4];
        ((uint4*)(kbf + o))[0] = *(uint4*)&uk[0];
        ((uint4*)(kbf + o))[1] = *(uint4*)&uk[4];
    }
}

// ---------------------------------------------------------------------------
// K2a: channel-map partial dot products: part[bh][ch][256] over one 256-n chunk.
// grid 72 = bh*9+ch. Parallelizes the old 8-block k_secm 9x.
// ---------------------------------------------------------------------------
__global__ __launch_bounds__(256) void k_secm_part(
    const float* __restrict__ x1f, const float* __restrict__ x2f, float* __restrict__ part)
{
    __shared__ float c1[256][16];
    __shared__ float c2[256][16];
    const int bh = blockIdx.x / NKCH;
    const int ch = blockIdx.x % NKCH;
    const int tid = threadIdx.x;
    const int i = tid >> 4, j = tid & 15;
    const float4* s1 = (const float4*)(x1f + ((size_t)bh * HW + ch * 256) * 16);
    const float4* s2 = (const float4*)(x2f + ((size_t)bh * HW + ch * 256) * 16);
    for (int t = tid; t < 1024; t += 256) { ((float4*)c1)[t] = s1[t]; ((float4*)c2)[t] = s2[t]; }
    __syncthreads();
    float acc = 0.f;
    #pragma unroll 8
    for (int nn = 0; nn < 256; ++nn) acc += c1[nn][i] * c2[nn][j];
    part[(size_t)blockIdx.x * 256 + tid] = acc;
}

// ---------------------------------------------------------------------------
// K2b: reduce partials + row softmax -> secm[bh][16][16]. 8 blocks.
// ---------------------------------------------------------------------------
__global__ __launch_bounds__(256) void k_secm_fin(
    const float* __restrict__ part, float* __restrict__ secm)
{
    __shared__ float S[256];
    const int bh = blockIdx.x;
    const int tid = threadIdx.x;
    const int i = tid >> 4;
    float acc = 0.f;
    #pragma unroll
    for (int c = 0; c < NKCH; ++c) acc += part[((size_t)bh * NKCH + c) * 256 + tid];
    acc *= (0.25f / 144.f);
    S[tid] = acc;
    __syncthreads();
    float mx = -1e30f;
    #pragma unroll
    for (int jj = 0; jj < 16; ++jj) mx = fmaxf(mx, S[i * 16 + jj]);
    float sum = 0.f;
    #pragma unroll
    for (int jj = 0; jj < 16; ++jj) sum += __expf(S[i * 16 + jj] - mx);
    secm[(size_t)bh * 256 + tid] = __expf(acc - mx) / sum;
}

// ---------------------------------------------------------------------------
// K3: fused MFMA spatial attention + softmax + channel gate -> outa.
// grid (72, 8): x = q-chunk of 32 rows, y = bh. block 128 = 2 waves, 1 q-tile each.
// S^T tile = mfma(K-frag, Q-frag) [d padded to 32, Q-frag zeroed for g>=2];
// P^T fed to PV mfma via per-wave LDS round-trip (no barriers needed).
// O^T accumulated in 4 f32/lane; epilogue: l-reduce (shfl), gate, store float4.
// ---------------------------------------------------------------------------
__global__ __launch_bounds__(128) void k_attn(
    const unsigned short* __restrict__ qbf, const unsigned short* __restrict__ kbf,
    const unsigned short* __restrict__ vtbf, const float* __restrict__ y1f,
    const float* __restrict__ secm, float* __restrict__ outa)
{
    __shared__ unsigned char kbuf[256 * 48];   // K chunk: 256 rows x 32B, +16B pad (2-way banks)
    __shared__ unsigned char vbuf[16 * 528];   // V^T chunk: 16 rows x 512B, +16B pad
    __shared__ unsigned char pbuf[2 * 16 * 80];// per-wave P^T tile: 16 q x 64B, +16B pad
    __shared__ float sm[256];                  // secm 16x16
    const int qc  = blockIdx.x;     // 0..71 (32 q rows each)
    const int bh  = blockIdx.y;     // 0..7
    const int tid = threadIdx.x;
    const int w    = tid >> 6;
    const int lane = tid & 63;
    const int q16  = lane & 15;     // q-col (also dd-row for PV A, k-row for S^T A)
    const int g    = lane >> 4;     // lane group 0..3
    sm[tid] = secm[(size_t)bh * 256 + tid];
    sm[tid + 128] = secm[(size_t)bh * 256 + tid + 128];
    const int qglob = qc * 32 + w * 16 + q16;

    // Q fragment (B operand of S^T): d = 8g..8g+7; zero for g>=2 (d-padding)
    bf16x8 qfrag = {0,0,0,0,0,0,0,0};
    if (g < 2) qfrag = *(const bf16x8*)(qbf + ((size_t)bh * HW + qglob) * 16 + g * 8);

    f32x4 oacc = {0.f, 0.f, 0.f, 0.f};
    float lsum = 0.f;
    unsigned char* pw = pbuf + w * 1280;
    const f32x4 zero4 = {0.f, 0.f, 0.f, 0.f};

    for (int kc = 0; kc < NKCH; ++kc) {
        __syncthreads();
        // stage K chunk: rows tid, tid+128 (32B each -> 48B-stride LDS rows)
        {
            const uint4* gk = (const uint4*)(kbf + ((size_t)bh * HW + kc * 256) * 16);
            #pragma unroll
            for (int rr = 0; rr < 2; ++rr) {
                const int r = tid + rr * 128;
                uint4 a = gk[2 * r], c = gk[2 * r + 1];
                *(uint4*)(kbuf + r * 48) = a;
                *(uint4*)(kbuf + r * 48 + 16) = c;
            }
            // stage V^T chunk: thread -> row dd=tid>>3, 64B segment (tid&7)
            const int dd = tid >> 3, pp = tid & 7;
            const uint4* gv = (const uint4*)(vtbf + ((size_t)bh * 16 + dd) * HW + kc * 256 + pp * 32);
            uint4 v0 = gv[0], v1 = gv[1], v2 = gv[2], v3 = gv[3];
            uint4* dst = (uint4*)(vbuf + dd * 528 + pp * 64);
            dst[0] = v0; dst[1] = v1; dst[2] = v2; dst[3] = v3;
        }
        __syncthreads();
        #pragma unroll
        for (int wi = 0; wi < 8; ++wi) {           // 32-k windows
            #pragma unroll
            for (int t = 0; t < 2; ++t) {          // two 16-k S^T tiles
                const int kt = wi * 2 + t;
                // K A-frag: row k=kt*16+q16, d=8*(g&1).. (dup for g>=2; killed by qfrag=0)
                bf16x8 kfrag = *(const bf16x8*)(kbuf + (kt * 16 + q16) * 48 + (g & 1) * 16);
                f32x4 s = __builtin_amdgcn_mfma_f32_16x16x32_bf16(kfrag, qfrag, zero4, 0, 0, 0);
                const float e0 = exp2f(s[0]), e1 = exp2f(s[1]);
                const float e2 = exp2f(s[2]), e3 = exp2f(s[3]);
                lsum += (e0 + e1) + (e2 + e3);
                const unsigned p01 = (unsigned)f2bf(e0) | ((unsigned)f2bf(e1) << 16);
                const unsigned p23 = (unsigned)f2bf(e2) | ((unsigned)f2bf(e3) << 16);
                // P^T[q16][k]: k = 16t + 4g + {0..3}
                *(unsigned*)(pw + q16 * 80 + (t * 16 + g * 4) * 2) = p01;
                *(unsigned*)(pw + q16 * 80 + (t * 16 + g * 4) * 2 + 4) = p23;
            }
            // PV: A = V^T frag (row dd=q16, k = wi*32+8g..+7), B = P^T frag (col q16, same k)
            bf16x8 vfrag = *(const bf16x8*)(vbuf + q16 * 528 + (wi * 32 + g * 8) * 2);
            bf16x8 pfrag = *(const bf16x8*)(pw + q16 * 80 + g * 16);
            oacc = __builtin_amdgcn_mfma_f32_16x16x32_bf16(vfrag, pfrag, oacc, 0, 0, 0);
        }
    }
    // softmax denominator: reduce lane partials across the 4 groups (same q16)
    lsum += __shfl_xor(lsum, 16);
    lsum += __shfl_xor(lsum, 32);
    const float invl = 1.f / lsum;
    // channel gate: out2[q, dd] = sum_i y1[q,i] * secm[i][dd],  dd = 4g+r
    const float* yrow = y1f + ((size_t)bh * HW + qglob) * 16;
    float gate[4] = {0.f, 0.f, 0.f, 0.f};
    #pragma unroll
    for (int i = 0; i < 16; ++i) {
        const float yv = yrow[i];
        #pragma unroll
        for (int r = 0; r < 4; ++r) gate[r] += yv * sm[i * 16 + g * 4 + r];
    }
    const int b = bh >> 2, h = bh & 3;
    float4 res;
    res.x = oacc[0] * invl * gate[0];
    res.y = oacc[1] * invl * gate[1];
    res.z = oacc[2] * invl * gate[2];
    res.w = oacc[3] * invl * gate[3];
    *(float4*)(outa + ((size_t)b * HW + qglob) * 64 + h * 16 + g * 4) = res;
}

// ---------------------------------------------------------------------------
// K4: attention out-proj + residual: xt2[b][q][c] = x^T + outa @ w_out + b_out
// ---------------------------------------------------------------------------
__global__ __launch_bounds__(256) void k_outproj(
    const float* __restrict__ outa, const float* __restrict__ x,
    const float* __restrict__ w_out, const float* __restrict__ b_out,
    float* __restrict__ xt2)
{
    __shared__ float ws[64][64];
    __shared__ float rows[64][65];
    const int b  = blockIdx.x / NQT;
    const int qt = blockIdx.x % NQT;
    const int tid = threadIdx.x;
    for (int t = tid; t < 4096; t += 256) ws[t >> 6][t & 63] = w_out[t];
    const float* rsrc = outa + ((size_t)b * HW + qt * 64) * 64;
    for (int t = tid; t < 4096; t += 256) rows[t >> 6][t & 63] = rsrc[t];
    __syncthreads();
    const int qs = tid & 63;
    const int grp = tid >> 6;
    const int q = qt * 64 + qs;
    float res[16];
    #pragma unroll 4
    for (int cc = 0; cc < 16; ++cc) {
        const int c = grp * 16 + cc;
        float a = b_out[c];
        #pragma unroll
        for (int k = 0; k < 64; ++k) a += rows[qs][k] * ws[k][c];
        a += x[(size_t)b * CH * HW + (size_t)c * HW + q];
        res[cc] = a;
    }
    float* o = xt2 + ((size_t)b * HW + q) * 64 + grp * 16;
    #pragma unroll
    for (int i = 0; i < 4; ++i) ((float4*)o)[i] = ((const float4*)res)[i];
}

// ---------------------------------------------------------------------------
// K5a: LN2 + MLP layer 1 + LeakyReLU. 8 rows per block.
// ---------------------------------------------------------------------------
__global__ __launch_bounds__(256) void k_mlp1(
    const float* __restrict__ xt2, const float* __restrict__ g2, const float* __restrict__ b2v,
    const float* __restrict__ w1, const float* __restrict__ b1,
    float* __restrict__ hid)
{
    __shared__ float raw[8][64];
    __shared__ float rn[8][64];
    __shared__ float mv[8][2];
    const int r0 = blockIdx.x * 8;
    const int tid = threadIdx.x;
    const float* src = xt2 + (size_t)r0 * 64;
    for (int t = tid; t < 512; t += 256) raw[t >> 6][t & 63] = src[t];
    __syncthreads();
    if (tid < 8) {
        float m = 0.f;
        #pragma unroll
        for (int c = 0; c < 64; ++c) m += raw[tid][c];
        m *= (1.f / 64.f);
        float var = 0.f;
        #pragma unroll
        for (int c = 0; c < 64; ++c) { float d = raw[tid][c] - m; var += d * d; }
        mv[tid][0] = m;
        mv[tid][1] = rsqrtf(var * (1.f / 64.f) + 1e-5f);
    }
    __syncthreads();
    for (int t = tid; t < 512; t += 256) {
        const int rr = t >> 6, c = t & 63;
        rn[rr][c] = (raw[rr][c] - mv[rr][0]) * mv[rr][1] * g2[c] + b2v[c];
    }
    __syncthreads();
    float acc[8];
    #pragma unroll
    for (int rr = 0; rr < 8; ++rr) acc[rr] = 0.f;
    for (int c = 0; c < 64; ++c) {
        const float wv = w1[(size_t)c * 256 + tid];
        #pragma unroll
        for (int rr = 0; rr < 8; ++rr) acc[rr] += rn[rr][c] * wv;
    }
    const float bv = b1[tid];
    #pragma unroll
    for (int rr = 0; rr < 8; ++rr) {
        const float a = acc[rr] + bv;
        hid[(size_t)(r0 + rr) * 256 + tid] = fmaxf(a, 0.01f * a);
    }
}

// ---------------------------------------------------------------------------
// K5b: MLP layer 2 + residual + transposed (B,C,H,W) output write.
// ---------------------------------------------------------------------------
__global__ __launch_bounds__(256) void k_mlp2(
    const float* __restrict__ hid, const float* __restrict__ xt2,
    const float* __restrict__ w2, const float* __restrict__ b2,
    float* __restrict__ out)
{
    __shared__ float hl[256][33];
    __shared__ float w2s[256][64];
    const int b  = blockIdx.x / 72;
    const int qt = blockIdx.x % 72;
    const int tid = threadIdx.x;
    for (int t = tid; t < 16384; t += 256) w2s[t >> 6][t & 63] = w2[t];
    const float* hsrc = hid + ((size_t)b * HW + qt * 32) * 256;
    for (int t = tid; t < 8192; t += 256) hl[t & 255][t >> 8] = hsrc[t];
    __syncthreads();
    const int qs = tid & 31;
    const int cg = tid >> 5;
    const int q = qt * 32 + qs;
    float accv[8];
    #pragma unroll
    for (int cc = 0; cc < 8; ++cc) {
        const int c = cg * 8 + cc;
        accv[cc] = b2[c] + xt2[((size_t)b * HW + q) * 64 + c];
    }
    #pragma unroll 4
    for (int j = 0; j < 256; ++j) {
        const float hv = hl[j][qs];
        #pragma unroll
        for (int cc = 0; cc < 8; ++cc) accv[cc] += hv * w2s[j][cg * 8 + cc];
    }
    #pragma unroll
    for (int cc = 0; cc < 8; ++cc) {
        const int c = cg * 8 + cc;
        out[(size_t)b * CH * HW + (size_t)c * HW + q] = accv[cc];
    }
}

extern "C" void kernel_launch(void* const* d_in, const int* in_sizes, int n_in,
                              void* d_out, int out_size, void* d_ws, size_t ws_size,
                              hipStream_t stream)
{
    (void)in_sizes; (void)n_in; (void)out_size; (void)ws_size;
    const float* x     = (const float*)d_in[0];
    const float* y     = (const float*)d_in[1];
    const float* ln1_g = (const float*)d_in[2];
    const float* ln1_b = (const float*)d_in[3];
    const float* w_sa1 = (const float*)d_in[4];
    const float* w_sa2 = (const float*)d_in[5];
    const float* w_se1 = (const float*)d_in[6];
    const float* w_se2 = (const float*)d_in[7];
    const float* w_out = (const float*)d_in[8];
    const float* b_out = (const float*)d_in[9];
    const float* ln2_g = (const float*)d_in[10];
    const float* ln2_b = (const float*)d_in[11];
    const float* w1    = (const float*)d_in[12];
    const float* b1    = (const float*)d_in[13];
    const float* w2    = (const float*)d_in[14];
    const float* b2    = (const float*)d_in[15];
    float* out = (float*)d_out;

    const size_t NP = 8ull * HW * 16;               // 294912
    float* p = (float*)d_ws;
    float* x1f  = p;  p += NP;
    float* x2f  = p;  p += NP;
    float* y1f  = p;  p += NP;
    float* outa = p;  p += NP;
    float* xt2  = p;  p += NP;
    float* hid  = p;  p += 2ull * HW * 256;
    float* spart= p;  p += 72 * 256;
    float* secm = p;  p += 2048;
    unsigned short* qbf  = (unsigned short*)p;
    unsigned short* kbf  = qbf + NP;
    unsigned short* vtbf = kbf + NP;
    // total ~10 MB of d_ws

    k_ln_proj<<<dim3(2 * NQT, 2), 256, 0, stream>>>(x, y, ln1_g, ln1_b,
                                                    w_sa1, w_sa2, w_se1, w_se2,
                                                    x1f, x2f, y1f, qbf, kbf, vtbf);
    k_secm_part<<<8 * NKCH, 256, 0, stream>>>(x1f, x2f, spart);
    k_secm_fin<<<8, 256, 0, stream>>>(spart, secm);
    k_attn<<<dim3(72, 8), 128, 0, stream>>>(qbf, kbf, vtbf, y1f, secm, outa);
    k_outproj<<<2 * NQT, 256, 0, stream>>>(outa, x, w_out, b_out, xt2);
    k_mlp1<<<2 * HW / 8, 256, 0, stream>>>(xt2, ln2_g, ln2_b, w1, b1, hid);
    k_mlp2<<<144, 256, 0, stream>>>(hid, xt2, w2, b2, out);
}

// Round 5
// 132.511 us; speedup vs baseline: 1.8543x; 1.4035x over previous
//
#include <hip/hip_runtime.h>

#define HW 2304          // n = 48*48
#define CH 64            // DIM
typedef unsigned short ushort_t;
typedef __attribute__((ext_vector_type(8))) short bf16x8;
typedef __attribute__((ext_vector_type(4))) float f32x4;

#define QSCL (0.25f * 1.44269504088896340736f)   // attn scale * log2(e), folded into Qbf
#define MFMA(a, b, c) __builtin_amdgcn_mfma_f32_16x16x32_bf16((a), (b), (c), 0, 0, 0)

static __device__ __forceinline__ ushort_t f2bf(float f) {
    union { float f; unsigned u; } v; v.f = f;
    unsigned r = v.u + 0x7FFFu + ((v.u >> 16) & 1u);   // RNE
    return (ushort_t)(r >> 16);
}
static __device__ __forceinline__ unsigned cvtpk(float a, float b) {  // lo=a, hi=b
    unsigned r;
    asm("v_cvt_pk_bf16_f32 %0, %1, %2" : "=v"(r) : "v"(a), "v"(b));
    return r;
}
union U8 { unsigned u[4]; bf16x8 v; };

// ---------------------------------------------------------------------------
// K0: transpose+convert all weights to bf16 [out_ch][in_ch] so MFMA B-frags
// are single b128 loads. 208 blocks x 256.
// ---------------------------------------------------------------------------
__global__ __launch_bounds__(256) void k_wconv(
    const float* __restrict__ wsa1, const float* __restrict__ wsa2,
    const float* __restrict__ wse1, const float* __restrict__ wse2,
    const float* __restrict__ w_out, const float* __restrict__ w1,
    const float* __restrict__ w2,
    ushort_t* __restrict__ wsa1T, ushort_t* __restrict__ wsa2T,
    ushort_t* __restrict__ wse1T, ushort_t* __restrict__ wse2T,
    ushort_t* __restrict__ w_outT, ushort_t* __restrict__ wT1, ushort_t* __restrict__ wT2)
{
    const int blk = blockIdx.x, tid = threadIdx.x;
    if (blk < 80) {                       // five 64x64 transposes
        const int mi = blk >> 4;
        const float* s = mi == 0 ? wsa1 : mi == 1 ? wsa2 : mi == 2 ? wse1 : mi == 3 ? wse2 : w_out;
        ushort_t* d = mi == 0 ? wsa1T : mi == 1 ? wsa2T : mi == 2 ? wse1T : mi == 3 ? wse2T : w_outT;
        const int o = (blk & 15) * 256 + tid;
        d[o] = f2bf(s[(o & 63) * 64 + (o >> 6)]);
    } else if (blk < 144) {               // wT1[j][c] = w1[c][j], j<256 c<64
        const int o = (blk - 80) * 256 + tid;
        wT1[o] = f2bf(w1[(o & 63) * 256 + (o >> 6)]);
    } else {                              // wT2[j][c] = w2[c][j], j<64 c<256
        const int o = (blk - 144) * 256 + tid;
        wT2[o] = f2bf(w2[(o & 255) * 64 + (o >> 8)]);
    }
}

// ---------------------------------------------------------------------------
// K1: LN + dual projection via MFMA. 1 wave / 16 rows. grid 576 x 64.
// task: rt = %144 (q-tile), b = (/144)&1, branch = /288.
// branch0 (x): proj1 -> vtbf (V^T bf16 [bh][16][HW]), proj2 -> x2t (same layout)
// branch1 (y): proj1 -> y1f f32 + qbf (*QSCL), proj2 -> kbf
// ---------------------------------------------------------------------------
__global__ __launch_bounds__(64) void k_ln_proj(
    const float* __restrict__ x, const float* __restrict__ y,
    const float* __restrict__ g, const float* __restrict__ bb,
    const ushort_t* __restrict__ wsa1T, const ushort_t* __restrict__ wsa2T,
    const ushort_t* __restrict__ wse1T, const ushort_t* __restrict__ wse2T,
    float* __restrict__ y1f, ushort_t* __restrict__ qbf, ushort_t* __restrict__ kbf,
    ushort_t* __restrict__ vtbf, ushort_t* __restrict__ x2t)
{
    const int task = blockIdx.x;
    const int rt = task % 144;
    const int b  = (task / 144) & 1;
    const int branch = task / 288;
    const int lane = threadIdx.x;
    const int r = lane & 15, cg = lane >> 4;
    const int q0 = rt * 16;
    const float* in = (branch ? y : x) + (size_t)b * CH * HW + q0 + r;
    float lo[8], hi[8];
    float s = 0.f, sq = 0.f;
    #pragma unroll
    for (int ki = 0; ki < 8; ++ki) {
        lo[ki] = in[(size_t)(8 * cg + ki) * HW];
        hi[ki] = in[(size_t)(32 + 8 * cg + ki) * HW];
        s += lo[ki] + hi[ki];
        sq += lo[ki] * lo[ki] + hi[ki] * hi[ki];
    }
    s  += __shfl_xor(s, 16);  s  += __shfl_xor(s, 32);
    sq += __shfl_xor(sq, 16); sq += __shfl_xor(sq, 32);
    const float m  = s * (1.f / 64.f);
    const float rs = rsqrtf(sq * (1.f / 64.f) - m * m + 1e-5f);
    float ga[16], be[16];   // gamma/beta for this lane's 16 channels (lo 8, hi 8)
    {
        const float4* gp = (const float4*)g;
        const float4* bp = (const float4*)bb;
        *(float4*)&ga[0]  = gp[2 * cg];     *(float4*)&ga[4]  = gp[2 * cg + 1];
        *(float4*)&ga[8]  = gp[8 + 2 * cg]; *(float4*)&ga[12] = gp[9 + 2 * cg];
        *(float4*)&be[0]  = bp[2 * cg];     *(float4*)&be[4]  = bp[2 * cg + 1];
        *(float4*)&be[8]  = bp[8 + 2 * cg]; *(float4*)&be[12] = bp[9 + 2 * cg];
    }
    float nlo[8], nhi[8];
    #pragma unroll
    for (int ki = 0; ki < 8; ++ki) {
        nlo[ki] = (lo[ki] - m) * rs * ga[ki]     + be[ki];
        nhi[ki] = (hi[ki] - m) * rs * ga[8 + ki] + be[8 + ki];
    }
    U8 alo, ahi;
    #pragma unroll
    for (int p = 0; p < 4; ++p) {
        alo.u[p] = cvtpk(nlo[2 * p], nlo[2 * p + 1]);
        ahi.u[p] = cvtpk(nhi[2 * p], nhi[2 * p + 1]);
    }
    const ushort_t* wp1 = branch ? wsa1T : wse1T;
    const ushort_t* wp2 = branch ? wsa2T : wse2T;
    #pragma unroll
    for (int jt = 0; jt < 4; ++jt) {
        const int bh = b * 4 + jt;
        // proj 1
        {
            bf16x8 bl = *(const bf16x8*)(wp1 + (jt * 16 + r) * 64 + 8 * cg);
            bf16x8 bh_ = *(const bf16x8*)(wp1 + (jt * 16 + r) * 64 + 32 + 8 * cg);
            f32x4 acc = {0.f, 0.f, 0.f, 0.f};
            acc = MFMA(alo.v, bl, acc);
            acc = MFMA(ahi.v, bh_, acc);
            if (branch == 0) {           // x1 -> V^T bf16
                uint2 pk; pk.x = cvtpk(acc[0], acc[1]); pk.y = cvtpk(acc[2], acc[3]);
                *(uint2*)(vtbf + (size_t)(bh * 16 + r) * HW + q0 + 4 * cg) = pk;
            } else {                     // y1 -> f32 + Q bf16 (*QSCL)
                #pragma unroll
                for (int ri = 0; ri < 4; ++ri) {
                    const int q = q0 + 4 * cg + ri;
                    y1f[((size_t)bh * HW + q) * 16 + r] = acc[ri];
                    qbf[((size_t)bh * HW + q) * 16 + r] = f2bf(acc[ri] * QSCL);
                }
            }
        }
        // proj 2
        {
            bf16x8 bl = *(const bf16x8*)(wp2 + (jt * 16 + r) * 64 + 8 * cg);
            bf16x8 bh_ = *(const bf16x8*)(wp2 + (jt * 16 + r) * 64 + 32 + 8 * cg);
            f32x4 acc = {0.f, 0.f, 0.f, 0.f};
            acc = MFMA(alo.v, bl, acc);
            acc = MFMA(ahi.v, bh_, acc);
            if (branch == 0) {           // x2 -> x2^T bf16
                uint2 pk; pk.x = cvtpk(acc[0], acc[1]); pk.y = cvtpk(acc[2], acc[3]);
                *(uint2*)(x2t + (size_t)(bh * 16 + r) * HW + q0 + 4 * cg) = pk;
            } else {                     // y2 -> K bf16
                #pragma unroll
                for (int ri = 0; ri < 4; ++ri) {
                    const int q = q0 + 4 * cg + ri;
                    kbf[((size_t)bh * HW + q) * 16 + r] = f2bf(acc[ri]);
                }
            }
        }
    }
}

// ---------------------------------------------------------------------------
// K2: channel map via MFMA on x1^T (=vtbf), x2^T. 8 blocks x 256 (4 waves
// k-split), LDS combine, wave0 does row softmax. secm[bh][16][16] f32.
// ---------------------------------------------------------------------------
__global__ __launch_bounds__(256) void k_secm(
    const ushort_t* __restrict__ vtbf, const ushort_t* __restrict__ x2t,
    float* __restrict__ secm)
{
    __shared__ f32x4 cacc[4][64];
    const int bh = blockIdx.x;
    const int tid = threadIdx.x;
    const int w = tid >> 6, lane = tid & 63;
    const int r = lane & 15, g = lane >> 4;
    const ushort_t* pa = vtbf + (size_t)(bh * 16 + r) * HW;
    const ushort_t* pb = x2t + (size_t)(bh * 16 + r) * HW;
    f32x4 acc = {0.f, 0.f, 0.f, 0.f};
    for (int wi = 0; wi < 18; ++wi) {
        const int k0 = w * 576 + wi * 32 + 8 * g;
        bf16x8 a = *(const bf16x8*)(pa + k0);
        bf16x8 bf_ = *(const bf16x8*)(pb + k0);
        acc = MFMA(a, bf_, acc);
    }
    cacc[w][lane] = acc;
    __syncthreads();
    if (tid < 64) {
        f32x4 t0 = cacc[0][lane], t1 = cacc[1][lane], t2 = cacc[2][lane], t3 = cacc[3][lane];
        #pragma unroll
        for (int ri = 0; ri < 4; ++ri) {
            const float v = (t0[ri] + t1[ri] + t2[ri] + t3[ri]) * (0.25f / 144.f);
            float mx = v;
            mx = fmaxf(mx, __shfl_xor(mx, 1)); mx = fmaxf(mx, __shfl_xor(mx, 2));
            mx = fmaxf(mx, __shfl_xor(mx, 4)); mx = fmaxf(mx, __shfl_xor(mx, 8));
            const float e = __expf(v - mx);
            float sm_ = e;
            sm_ += __shfl_xor(sm_, 1); sm_ += __shfl_xor(sm_, 2);
            sm_ += __shfl_xor(sm_, 4); sm_ += __shfl_xor(sm_, 8);
            secm[bh * 256 + (4 * g + ri) * 16 + r] = e / sm_;
        }
    }
}

// ---------------------------------------------------------------------------
// K3: barrier-free MFMA attention. grid (144, 8) x 256 (4 waves).
// Wave w: this block's 16-q tile over k in [w*576, w*576+576), K/V fragments
// read DIRECT from global (L2-resident). Per-wave LDS P round-trip only.
// One barrier merges 4 partial (O^T, l); wave0 gates + stores obf bf16.
// ---------------------------------------------------------------------------
__global__ __launch_bounds__(256, 4) void k_attn(
    const ushort_t* __restrict__ qbf, const ushort_t* __restrict__ kbf,
    const ushort_t* __restrict__ vtbf, const float* __restrict__ y1f,
    const float* __restrict__ secm, ushort_t* __restrict__ obf)
{
    __shared__ uint4 pbuf4[4][80];          // per-wave P^T tile: 16 q x 80B
    __shared__ f32x4 cacc[4][64];
    __shared__ float clsum[4][64];
    __shared__ float smv[256];
    const int qt = blockIdx.x, bh = blockIdx.y;
    const int tid = threadIdx.x;
    const int w = tid >> 6, lane = tid & 63;
    const int q16 = lane & 15, g = lane >> 4;
    const int q0 = qt * 16;
    smv[tid] = secm[bh * 256 + tid];

    bf16x8 qfrag = {0, 0, 0, 0, 0, 0, 0, 0};
    if (g < 2) qfrag = *(const bf16x8*)(qbf + ((size_t)bh * HW + q0 + q16) * 16 + g * 8);

    unsigned char* pw = (unsigned char*)&pbuf4[w][0];
    const ushort_t* kbase = kbf + (size_t)bh * HW * 16;
    const ushort_t* vbase = vtbf + (size_t)(bh * 16 + q16) * HW;
    f32x4 oacc = {0.f, 0.f, 0.f, 0.f};
    float lsum = 0.f;
    const f32x4 zero4 = {0.f, 0.f, 0.f, 0.f};

    #pragma unroll 2
    for (int wi = 0; wi < 18; ++wi) {
        const int k0 = w * 576 + wi * 32;
        bf16x8 kf0 = *(const bf16x8*)(kbase + (size_t)(k0 + q16) * 16 + (g & 1) * 8);
        bf16x8 kf1 = *(const bf16x8*)(kbase + (size_t)(k0 + 16 + q16) * 16 + (g & 1) * 8);
        f32x4 s0 = MFMA(kf0, qfrag, zero4);
        f32x4 s1 = MFMA(kf1, qfrag, zero4);
        const float e00 = exp2f(s0[0]), e01 = exp2f(s0[1]), e02 = exp2f(s0[2]), e03 = exp2f(s0[3]);
        const float e10 = exp2f(s1[0]), e11 = exp2f(s1[1]), e12 = exp2f(s1[2]), e13 = exp2f(s1[3]);
        lsum += ((e00 + e01) + (e02 + e03)) + ((e10 + e11) + (e12 + e13));
        *(unsigned*)(pw + q16 * 80 + 8 * g)      = cvtpk(e00, e01);
        *(unsigned*)(pw + q16 * 80 + 8 * g + 4)  = cvtpk(e02, e03);
        *(unsigned*)(pw + q16 * 80 + 32 + 8 * g) = cvtpk(e10, e11);
        *(unsigned*)(pw + q16 * 80 + 36 + 8 * g) = cvtpk(e12, e13);
        bf16x8 vfrag = *(const bf16x8*)(vbase + k0 + 8 * g);
        bf16x8 pfrag = *(const bf16x8*)(pw + q16 * 80 + 16 * g);
        oacc = MFMA(vfrag, pfrag, oacc);
    }
    cacc[w][lane] = oacc;
    clsum[w][lane] = lsum;
    __syncthreads();
    if (tid < 64) {
        f32x4 t0 = cacc[0][lane], t1 = cacc[1][lane], t2 = cacc[2][lane], t3 = cacc[3][lane];
        float L = clsum[0][lane] + clsum[1][lane] + clsum[2][lane] + clsum[3][lane];
        L += __shfl_xor(L, 16);
        L += __shfl_xor(L, 32);
        const float invl = 1.f / L;
        const float* yrow = y1f + ((size_t)bh * HW + q0 + q16) * 16;
        float ya[16];
        #pragma unroll
        for (int i = 0; i < 4; ++i) *(float4*)&ya[4 * i] = ((const float4*)yrow)[i];
        float gate[4] = {0.f, 0.f, 0.f, 0.f};
        #pragma unroll
        for (int i = 0; i < 16; ++i) {
            #pragma unroll
            for (int rr = 0; rr < 4; ++rr) gate[rr] += ya[i] * smv[i * 16 + g * 4 + rr];
        }
        const int b = bh >> 2, h = bh & 3;
        float r0 = (t0[0] + t1[0] + t2[0] + t3[0]) * invl * gate[0];
        float r1 = (t0[1] + t1[1] + t2[1] + t3[1]) * invl * gate[1];
        float r2 = (t0[2] + t1[2] + t2[2] + t3[2]) * invl * gate[2];
        float r3 = (t0[3] + t1[3] + t2[3] + t3[3]) * invl * gate[3];
        uint2 pk; pk.x = cvtpk(r0, r1); pk.y = cvtpk(r2, r3);
        *(uint2*)(obf + ((size_t)b * HW + q0 + q16) * 64 + h * 16 + g * 4) = pk;
    }
}

// ---------------------------------------------------------------------------
// K4: out-proj + residual via MFMA. 1 wave / 16 rows. grid 288 x 64.
// xt2[b][q][64] = x^T + obf @ w_out + b_out  (f32)
// ---------------------------------------------------------------------------
__global__ __launch_bounds__(64) void k_outproj(
    const ushort_t* __restrict__ obf, const float* __restrict__ x,
    const ushort_t* __restrict__ w_outT, const float* __restrict__ b_out,
    float* __restrict__ xt2)
{
    const int t = blockIdx.x;
    const int b = t / 144, rt = t % 144;
    const int lane = threadIdx.x, r = lane & 15, cg = lane >> 4;
    const int q0 = rt * 16;
    const ushort_t* arow = obf + ((size_t)b * HW + q0 + r) * 64;
    bf16x8 alo = *(const bf16x8*)(arow + 8 * cg);
    bf16x8 ahi = *(const bf16x8*)(arow + 32 + 8 * cg);
    #pragma unroll
    for (int jt = 0; jt < 4; ++jt) {
        bf16x8 bl = *(const bf16x8*)(w_outT + (jt * 16 + r) * 64 + 8 * cg);
        bf16x8 bh_ = *(const bf16x8*)(w_outT + (jt * 16 + r) * 64 + 32 + 8 * cg);
        f32x4 acc = {0.f, 0.f, 0.f, 0.f};
        acc = MFMA(alo, bl, acc);
        acc = MFMA(ahi, bh_, acc);
        const int c = jt * 16 + r;
        const float bo = b_out[c];
        float4 xr = *(const float4*)(x + (size_t)b * CH * HW + (size_t)c * HW + q0 + 4 * cg);
        float res[4] = {acc[0] + bo + xr.x, acc[1] + bo + xr.y,
                        acc[2] + bo + xr.z, acc[3] + bo + xr.w};
        #pragma unroll
        for (int ri = 0; ri < 4; ++ri)
            xt2[((size_t)b * HW + q0 + 4 * cg + ri) * 64 + c] = res[ri];
    }
}

// ---------------------------------------------------------------------------
// K5: LN2 + MLP1 + LeakyReLU via MFMA. 1 wave / 16 rows. grid 288 x 64.
// hidb bf16 [row][256].
// ---------------------------------------------------------------------------
__global__ __launch_bounds__(64) void k_mlp1(
    const float* __restrict__ xt2, const float* __restrict__ g2, const float* __restrict__ b2v,
    const ushort_t* __restrict__ wT1, const float* __restrict__ b1,
    ushort_t* __restrict__ hidb)
{
    const int t = blockIdx.x;
    const int lane = threadIdx.x, r = lane & 15, cg = lane >> 4;
    const size_t row = (size_t)t * 16 + r;
    const float* src = xt2 + row * 64;
    float lo[8], hi[8];
    *(float4*)&lo[0] = *(const float4*)(src + 8 * cg);
    *(float4*)&lo[4] = *(const float4*)(src + 8 * cg + 4);
    *(float4*)&hi[0] = *(const float4*)(src + 32 + 8 * cg);
    *(float4*)&hi[4] = *(const float4*)(src + 32 + 8 * cg + 4);
    float s = 0.f, sq = 0.f;
    #pragma unroll
    for (int ki = 0; ki < 8; ++ki) {
        s += lo[ki] + hi[ki];
        sq += lo[ki] * lo[ki] + hi[ki] * hi[ki];
    }
    s  += __shfl_xor(s, 16);  s  += __shfl_xor(s, 32);
    sq += __shfl_xor(sq, 16); sq += __shfl_xor(sq, 32);
    const float m  = s * (1.f / 64.f);
    const float rs = rsqrtf(sq * (1.f / 64.f) - m * m + 1e-5f);
    float ga[16], be[16];
    {
        const float4* gp = (const float4*)g2;
        const float4* bp = (const float4*)b2v;
        *(float4*)&ga[0]  = gp[2 * cg];     *(float4*)&ga[4]  = gp[2 * cg + 1];
        *(float4*)&ga[8]  = gp[8 + 2 * cg]; *(float4*)&ga[12] = gp[9 + 2 * cg];
        *(float4*)&be[0]  = bp[2 * cg];     *(float4*)&be[4]  = bp[2 * cg + 1];
        *(float4*)&be[8]  = bp[8 + 2 * cg]; *(float4*)&be[12] = bp[9 + 2 * cg];
    }
    float nlo[8], nhi[8];
    #pragma unroll
    for (int ki = 0; ki < 8; ++ki) {
        nlo[ki] = (lo[ki] - m) * rs * ga[ki]     + be[ki];
        nhi[ki] = (hi[ki] - m) * rs * ga[8 + ki] + be[8 + ki];
    }
    U8 alo, ahi;
    #pragma unroll
    for (int p = 0; p < 4; ++p) {
        alo.u[p] = cvtpk(nlo[2 * p], nlo[2 * p + 1]);
        ahi.u[p] = cvtpk(nhi[2 * p], nhi[2 * p + 1]);
    }
    const size_t row0 = (size_t)t * 16;
    #pragma unroll 4
    for (int jt = 0; jt < 16; ++jt) {
        bf16x8 bl = *(const bf16x8*)(wT1 + (jt * 16 + r) * 64 + 8 * cg);
        bf16x8 bh_ = *(const bf16x8*)(wT1 + (jt * 16 + r) * 64 + 32 + 8 * cg);
        f32x4 acc = {0.f, 0.f, 0.f, 0.f};
        acc = MFMA(alo.v, bl, acc);
        acc = MFMA(ahi.v, bh_, acc);
        const int c = jt * 16 + r;
        const float bias = b1[c];
        #pragma unroll
        for (int ri = 0; ri < 4; ++ri) {
            float v = acc[ri] + bias;
            v = fmaxf(v, 0.01f * v);
            hidb[(row0 + 4 * cg + ri) * 256 + c] = f2bf(v);
        }
    }
}

// ---------------------------------------------------------------------------
// K6: MLP2 + residual + transposed (B,C,H,W) store via MFMA. grid 288 x 64.
// ---------------------------------------------------------------------------
__global__ __launch_bounds__(64) void k_mlp2(
    const ushort_t* __restrict__ hidb, const float* __restrict__ xt2,
    const ushort_t* __restrict__ wT2, const float* __restrict__ b2,
    float* __restrict__ out)
{
    const int t = blockIdx.x;
    const int b = t / 144;
    const int q0l = (t % 144) * 16;
    const int lane = threadIdx.x, r = lane & 15, cg = lane >> 4;
    const size_t grow = (size_t)t * 16 + r;
    bf16x8 a[8];
    #pragma unroll
    for (int kw = 0; kw < 8; ++kw)
        a[kw] = *(const bf16x8*)(hidb + grow * 256 + kw * 32 + 8 * cg);
    #pragma unroll
    for (int jt = 0; jt < 4; ++jt) {
        f32x4 acc = {0.f, 0.f, 0.f, 0.f};
        #pragma unroll
        for (int kw = 0; kw < 8; ++kw) {
            bf16x8 bf_ = *(const bf16x8*)(wT2 + (jt * 16 + r) * 256 + kw * 32 + 8 * cg);
            acc = MFMA(a[kw], bf_, acc);
        }
        const int c = jt * 16 + r;
        const float bias = b2[c];
        float res[4];
        #pragma unroll
        for (int ri = 0; ri < 4; ++ri)
            res[ri] = acc[ri] + bias + xt2[((size_t)t * 16 + 4 * cg + ri) * 64 + c];
        *(float4*)(out + (size_t)b * CH * HW + (size_t)c * HW + q0l + 4 * cg) = *(float4*)res;
    }
}

extern "C" void kernel_launch(void* const* d_in, const int* in_sizes, int n_in,
                              void* d_out, int out_size, void* d_ws, size_t ws_size,
                              hipStream_t stream)
{
    (void)in_sizes; (void)n_in; (void)out_size; (void)ws_size;
    const float* x     = (const float*)d_in[0];
    const float* y     = (const float*)d_in[1];
    const float* ln1_g = (const float*)d_in[2];
    const float* ln1_b = (const float*)d_in[3];
    const float* w_sa1 = (const float*)d_in[4];
    const float* w_sa2 = (const float*)d_in[5];
    const float* w_se1 = (const float*)d_in[6];
    const float* w_se2 = (const float*)d_in[7];
    const float* w_out = (const float*)d_in[8];
    const float* b_out = (const float*)d_in[9];
    const float* ln2_g = (const float*)d_in[10];
    const float* ln2_b = (const float*)d_in[11];
    const float* w1    = (const float*)d_in[12];
    const float* b1    = (const float*)d_in[13];
    const float* w2    = (const float*)d_in[14];
    const float* b2    = (const float*)d_in[15];
    float* out = (float*)d_out;

    const size_t NP = 8ull * HW * 16;              // 294912
    float* p = (float*)d_ws;
    float* y1f  = p;  p += NP;
    float* xt2  = p;  p += NP;
    float* secm = p;  p += 2048;
    ushort_t* u = (ushort_t*)p;
    ushort_t* qbf   = u;  u += NP;
    ushort_t* kbf   = u;  u += NP;
    ushort_t* vtbf  = u;  u += NP;
    ushort_t* x2t   = u;  u += NP;
    ushort_t* obf   = u;  u += NP;
    ushort_t* hidb  = u;  u += 4608ull * 256;
    ushort_t* wsa1T = u;  u += 4096;
    ushort_t* wsa2T = u;  u += 4096;
    ushort_t* wse1T = u;  u += 4096;
    ushort_t* wse2T = u;  u += 4096;
    ushort_t* w_outT= u;  u += 4096;
    ushort_t* wT1   = u;  u += 16384;
    ushort_t* wT2   = u;  u += 16384;
    // total ~8 MB of d_ws

    k_wconv<<<208, 256, 0, stream>>>(w_sa1, w_sa2, w_se1, w_se2, w_out, w1, w2,
                                     wsa1T, wsa2T, wse1T, wse2T, w_outT, wT1, wT2);
    k_ln_proj<<<576, 64, 0, stream>>>(x, y, ln1_g, ln1_b,
                                      wsa1T, wsa2T, wse1T, wse2T,
                                      y1f, qbf, kbf, vtbf, x2t);
    k_secm<<<8, 256, 0, stream>>>(vtbf, x2t, secm);
    k_attn<<<dim3(144, 8), 256, 0, stream>>>(qbf, kbf, vtbf, y1f, secm, obf);
    k_outproj<<<288, 64, 0, stream>>>(obf, x, w_outT, b_out, xt2);
    k_mlp1<<<288, 64, 0, stream>>>(xt2, ln2_g, ln2_b, wT1, b1, hidb);
    k_mlp2<<<288, 64, 0, stream>>>(hidb, xt2, wT2, b2, out);
}

// Round 6
// 126.923 us; speedup vs baseline: 1.9359x; 1.0440x over previous
//
#include <hip/hip_runtime.h>

#define HW 2304          // n = 48*48
#define CH 64            // DIM
typedef unsigned short ushort_t;
typedef __attribute__((ext_vector_type(8))) short bf16x8;
typedef __attribute__((ext_vector_type(4))) float f32x4;

#define QSCL (0.25f * 1.44269504088896340736f)   // attn scale * log2(e), folded into Qbf
#define SECM_SCL (0.25f / 144.f)
#define MFMA(a, b, c) __builtin_amdgcn_mfma_f32_16x16x32_bf16((a), (b), (c), 0, 0, 0)

static __device__ __forceinline__ ushort_t f2bf(float f) {
    union { float f; unsigned u; } v; v.f = f;
    unsigned r = v.u + 0x7FFFu + ((v.u >> 16) & 1u);   // RNE
    return (ushort_t)(r >> 16);
}
static __device__ __forceinline__ unsigned cvtpk(float a, float b) {  // lo=a, hi=b
    unsigned r;
    asm("v_cvt_pk_bf16_f32 %0, %1, %2" : "=v"(r) : "v"(a), "v"(b));
    return r;
}
union U8 { unsigned u[4]; bf16x8 v; };

// ---------------------------------------------------------------------------
// K0: weights -> bf16 [out][in]; blocks 0..7 also zero sacc (runs before
// ln_proj on the serial stream, so no separate memset launch).
// ---------------------------------------------------------------------------
__global__ __launch_bounds__(256) void k_wconv(
    const float* __restrict__ wsa1, const float* __restrict__ wsa2,
    const float* __restrict__ wse1, const float* __restrict__ wse2,
    const float* __restrict__ w_out, const float* __restrict__ w1,
    const float* __restrict__ w2,
    ushort_t* __restrict__ wsa1T, ushort_t* __restrict__ wsa2T,
    ushort_t* __restrict__ wse1T, ushort_t* __restrict__ wse2T,
    ushort_t* __restrict__ w_outT, ushort_t* __restrict__ wT1, ushort_t* __restrict__ wT2,
    float* __restrict__ sacc)
{
    const int blk = blockIdx.x, tid = threadIdx.x;
    if (blk < 8) sacc[blk * 256 + tid] = 0.f;
    if (blk < 80) {                       // five 64x64 transposes
        const int mi = blk >> 4;
        const float* s = mi == 0 ? wsa1 : mi == 1 ? wsa2 : mi == 2 ? wse1 : mi == 3 ? wse2 : w_out;
        ushort_t* d = mi == 0 ? wsa1T : mi == 1 ? wsa2T : mi == 2 ? wse1T : mi == 3 ? wse2T : w_outT;
        const int o = (blk & 15) * 256 + tid;
        d[o] = f2bf(s[(o & 63) * 64 + (o >> 6)]);
    } else if (blk < 144) {               // wT1[j][c] = w1[c][j]
        const int o = (blk - 80) * 256 + tid;
        wT1[o] = f2bf(w1[(o & 63) * 256 + (o >> 6)]);
    } else {                              // wT2[j][c] = w2[c][j]
        const int o = (blk - 144) * 256 + tid;
        wT2[o] = f2bf(w2[(o & 255) * 64 + (o >> 8)]);
    }
}

// ---------------------------------------------------------------------------
// K1: LN + dual projection via MFMA; branch-0 additionally accumulates the
// channel-map partials (x1^T x2 over its 16 rows) into sacc via one MFMA per
// head (LDS [d][row] transpose, k padded 16->32 with zero frags) + atomicAdd.
// grid 576 x 64 (1 wave / 16 rows).
// ---------------------------------------------------------------------------
__global__ __launch_bounds__(64) void k_ln_proj(
    const float* __restrict__ x, const float* __restrict__ y,
    const float* __restrict__ g, const float* __restrict__ bb,
    const ushort_t* __restrict__ wsa1T, const ushort_t* __restrict__ wsa2T,
    const ushort_t* __restrict__ wse1T, const ushort_t* __restrict__ wse2T,
    float* __restrict__ y1f, ushort_t* __restrict__ qbf, ushort_t* __restrict__ kbf,
    ushort_t* __restrict__ vtbf, float* __restrict__ sacc)
{
    __shared__ ushort_t ldsA[16 * 24 + 32];   // x1^T tile [d][row], 48B stride
    __shared__ ushort_t ldsB[16 * 24 + 32];   // x2^T tile
    const int task = blockIdx.x;
    const int rt = task % 144;
    const int b  = (task / 144) & 1;
    const int branch = task / 288;
    const int lane = threadIdx.x;
    const int r = lane & 15, cg = lane >> 4;
    const int q0 = rt * 16;
    const float* in = (branch ? y : x) + (size_t)b * CH * HW + q0 + r;
    float lo[8], hi[8];
    float s = 0.f, sq = 0.f;
    #pragma unroll
    for (int ki = 0; ki < 8; ++ki) {
        lo[ki] = in[(size_t)(8 * cg + ki) * HW];
        hi[ki] = in[(size_t)(32 + 8 * cg + ki) * HW];
        s += lo[ki] + hi[ki];
        sq += lo[ki] * lo[ki] + hi[ki] * hi[ki];
    }
    s  += __shfl_xor(s, 16);  s  += __shfl_xor(s, 32);
    sq += __shfl_xor(sq, 16); sq += __shfl_xor(sq, 32);
    const float m  = s * (1.f / 64.f);
    const float rs = rsqrtf(sq * (1.f / 64.f) - m * m + 1e-5f);
    float ga[16], be[16];
    {
        const float4* gp = (const float4*)g;
        const float4* bp = (const float4*)bb;
        *(float4*)&ga[0]  = gp[2 * cg];     *(float4*)&ga[4]  = gp[2 * cg + 1];
        *(float4*)&ga[8]  = gp[8 + 2 * cg]; *(float4*)&ga[12] = gp[9 + 2 * cg];
        *(float4*)&be[0]  = bp[2 * cg];     *(float4*)&be[4]  = bp[2 * cg + 1];
        *(float4*)&be[8]  = bp[8 + 2 * cg]; *(float4*)&be[12] = bp[9 + 2 * cg];
    }
    float nlo[8], nhi[8];
    #pragma unroll
    for (int ki = 0; ki < 8; ++ki) {
        nlo[ki] = (lo[ki] - m) * rs * ga[ki]     + be[ki];
        nhi[ki] = (hi[ki] - m) * rs * ga[8 + ki] + be[8 + ki];
    }
    U8 alo, ahi;
    #pragma unroll
    for (int p = 0; p < 4; ++p) {
        alo.u[p] = cvtpk(nlo[2 * p], nlo[2 * p + 1]);
        ahi.u[p] = cvtpk(nhi[2 * p], nhi[2 * p + 1]);
    }
    const ushort_t* wp1 = branch ? wsa1T : wse1T;
    const ushort_t* wp2 = branch ? wsa2T : wse2T;
    const f32x4 zero4 = {0.f, 0.f, 0.f, 0.f};
    #pragma unroll
    for (int jt = 0; jt < 4; ++jt) {
        const int bh = b * 4 + jt;
        bf16x8 bl1 = *(const bf16x8*)(wp1 + (jt * 16 + r) * 64 + 8 * cg);
        bf16x8 bh1 = *(const bf16x8*)(wp1 + (jt * 16 + r) * 64 + 32 + 8 * cg);
        f32x4 acc1 = zero4;
        acc1 = MFMA(alo.v, bl1, acc1);
        acc1 = MFMA(ahi.v, bh1, acc1);
        bf16x8 bl2 = *(const bf16x8*)(wp2 + (jt * 16 + r) * 64 + 8 * cg);
        bf16x8 bh2 = *(const bf16x8*)(wp2 + (jt * 16 + r) * 64 + 32 + 8 * cg);
        f32x4 acc2 = zero4;
        acc2 = MFMA(alo.v, bl2, acc2);
        acc2 = MFMA(ahi.v, bh2, acc2);
        if (branch == 0) {
            // x1 -> V^T bf16 global; x1,x2 -> per-wave LDS [d][row] tiles
            uint2 pk1; pk1.x = cvtpk(acc1[0], acc1[1]); pk1.y = cvtpk(acc1[2], acc1[3]);
            *(uint2*)(vtbf + (size_t)(bh * 16 + r) * HW + q0 + 4 * cg) = pk1;
            *(uint2*)&ldsA[r * 24 + 4 * cg] = pk1;
            uint2 pk2; pk2.x = cvtpk(acc2[0], acc2[1]); pk2.y = cvtpk(acc2[2], acc2[3]);
            *(uint2*)&ldsB[r * 24 + 4 * cg] = pk2;
            bf16x8 af = {0, 0, 0, 0, 0, 0, 0, 0};
            bf16x8 bf_ = {0, 0, 0, 0, 0, 0, 0, 0};
            if (cg < 2) {
                af  = *(const bf16x8*)&ldsA[r * 24 + 8 * cg];
                bf_ = *(const bf16x8*)&ldsB[r * 24 + 8 * cg];
            }
            f32x4 sp = MFMA(af, bf_, zero4);
            #pragma unroll
            for (int ri = 0; ri < 4; ++ri)
                atomicAdd(&sacc[bh * 256 + (4 * cg + ri) * 16 + r], sp[ri]);
        } else {
            #pragma unroll
            for (int ri = 0; ri < 4; ++ri) {
                const int q = q0 + 4 * cg + ri;
                y1f[((size_t)bh * HW + q) * 16 + r] = acc1[ri];
                qbf[((size_t)bh * HW + q) * 16 + r] = f2bf(acc1[ri] * QSCL);
                kbf[((size_t)bh * HW + q) * 16 + r] = f2bf(acc2[ri]);
            }
        }
    }
}

// ---------------------------------------------------------------------------
// K2: barrier-free MFMA attention; prologue computes the channel softmax
// from raw sacc sums (scale folded). grid (144, 8) x 256 (4 k-split waves).
// ---------------------------------------------------------------------------
__global__ __launch_bounds__(256, 4) void k_attn(
    const ushort_t* __restrict__ qbf, const ushort_t* __restrict__ kbf,
    const ushort_t* __restrict__ vtbf, const float* __restrict__ y1f,
    const float* __restrict__ sacc, ushort_t* __restrict__ obf)
{
    __shared__ uint4 pbuf4[4][80];          // per-wave P^T tile: 16 q x 80B
    __shared__ f32x4 cacc[4][64];
    __shared__ float clsum[4][64];
    __shared__ float sraw[256];
    __shared__ float smv[256];
    const int qt = blockIdx.x, bh = blockIdx.y;
    const int tid = threadIdx.x;
    const int w = tid >> 6, lane = tid & 63;
    const int q16 = lane & 15, g = lane >> 4;
    const int q0 = qt * 16;
    // channel-map softmax prologue (row i over cols j)
    const float v = sacc[bh * 256 + tid] * SECM_SCL;
    sraw[tid] = v;
    __syncthreads();
    {
        const int i = tid >> 4;
        float mx = -1e30f;
        #pragma unroll
        for (int jj = 0; jj < 16; ++jj) mx = fmaxf(mx, sraw[i * 16 + jj]);
        float sum = 0.f;
        #pragma unroll
        for (int jj = 0; jj < 16; ++jj) sum += __expf(sraw[i * 16 + jj] - mx);
        smv[tid] = __expf(v - mx) / sum;    // consumed after the post-loop barrier
    }

    bf16x8 qfrag = {0, 0, 0, 0, 0, 0, 0, 0};
    if (g < 2) qfrag = *(const bf16x8*)(qbf + ((size_t)bh * HW + q0 + q16) * 16 + g * 8);

    unsigned char* pw = (unsigned char*)&pbuf4[w][0];
    const ushort_t* kbase = kbf + (size_t)bh * HW * 16;
    const ushort_t* vbase = vtbf + (size_t)(bh * 16 + q16) * HW;
    f32x4 oacc = {0.f, 0.f, 0.f, 0.f};
    float lsum = 0.f;
    const f32x4 zero4 = {0.f, 0.f, 0.f, 0.f};

    #pragma unroll 2
    for (int wi = 0; wi < 18; ++wi) {
        const int k0 = w * 576 + wi * 32;
        bf16x8 kf0 = *(const bf16x8*)(kbase + (size_t)(k0 + q16) * 16 + (g & 1) * 8);
        bf16x8 kf1 = *(const bf16x8*)(kbase + (size_t)(k0 + 16 + q16) * 16 + (g & 1) * 8);
        f32x4 s0 = MFMA(kf0, qfrag, zero4);
        f32x4 s1 = MFMA(kf1, qfrag, zero4);
        const float e00 = exp2f(s0[0]), e01 = exp2f(s0[1]), e02 = exp2f(s0[2]), e03 = exp2f(s0[3]);
        const float e10 = exp2f(s1[0]), e11 = exp2f(s1[1]), e12 = exp2f(s1[2]), e13 = exp2f(s1[3]);
        lsum += ((e00 + e01) + (e02 + e03)) + ((e10 + e11) + (e12 + e13));
        *(unsigned*)(pw + q16 * 80 + 8 * g)      = cvtpk(e00, e01);
        *(unsigned*)(pw + q16 * 80 + 8 * g + 4)  = cvtpk(e02, e03);
        *(unsigned*)(pw + q16 * 80 + 32 + 8 * g) = cvtpk(e10, e11);
        *(unsigned*)(pw + q16 * 80 + 36 + 8 * g) = cvtpk(e12, e13);
        bf16x8 vfrag = *(const bf16x8*)(vbase + k0 + 8 * g);
        bf16x8 pfrag = *(const bf16x8*)(pw + q16 * 80 + 16 * g);
        oacc = MFMA(vfrag, pfrag, oacc);
    }
    cacc[w][lane] = oacc;
    clsum[w][lane] = lsum;
    __syncthreads();
    if (tid < 64) {
        f32x4 t0 = cacc[0][lane], t1 = cacc[1][lane], t2 = cacc[2][lane], t3 = cacc[3][lane];
        float L = clsum[0][lane] + clsum[1][lane] + clsum[2][lane] + clsum[3][lane];
        L += __shfl_xor(L, 16);
        L += __shfl_xor(L, 32);
        const float invl = 1.f / L;
        const float* yrow = y1f + ((size_t)bh * HW + q0 + q16) * 16;
        float ya[16];
        #pragma unroll
        for (int i = 0; i < 4; ++i) *(float4*)&ya[4 * i] = ((const float4*)yrow)[i];
        float gate[4] = {0.f, 0.f, 0.f, 0.f};
        #pragma unroll
        for (int i = 0; i < 16; ++i) {
            #pragma unroll
            for (int rr = 0; rr < 4; ++rr) gate[rr] += ya[i] * smv[i * 16 + g * 4 + rr];
        }
        const int b = bh >> 2, h = bh & 3;
        float r0 = (t0[0] + t1[0] + t2[0] + t3[0]) * invl * gate[0];
        float r1 = (t0[1] + t1[1] + t2[1] + t3[1]) * invl * gate[1];
        float r2 = (t0[2] + t1[2] + t2[2] + t3[2]) * invl * gate[2];
        float r3 = (t0[3] + t1[3] + t2[3] + t3[3]) * invl * gate[3];
        uint2 pk; pk.x = cvtpk(r0, r1); pk.y = cvtpk(r2, r3);
        *(uint2*)(obf + ((size_t)b * HW + q0 + q16) * 64 + h * 16 + g * 4) = pk;
    }
}

// ---------------------------------------------------------------------------
// K3: fused tail: out-proj + residual -> LN2 -> MLP1+LeakyReLU -> MLP2 +
// residual -> transposed store. 1 wave / 16 rows, grid 288 x 64. xt2 tile
// stays in registers (mlp2 residual register-local); fragment re-layouts via
// same-wave LDS round-trips (16B-aligned strides).
// ---------------------------------------------------------------------------
__global__ __launch_bounds__(64) void k_tail(
    const ushort_t* __restrict__ obf, const float* __restrict__ x,
    const ushort_t* __restrict__ w_outT, const float* __restrict__ b_out,
    const float* __restrict__ g2, const float* __restrict__ bt2,
    const ushort_t* __restrict__ wT1, const float* __restrict__ b1,
    const ushort_t* __restrict__ wT2, const float* __restrict__ b2,
    float* __restrict__ out)
{
    __shared__ ushort_t xn[16 * 72 + 16];    // LN2 output, [row][ch], 144B stride
    __shared__ ushort_t hh[16 * 264 + 16];   // hidden, [row][ch], 528B stride
    const int t = blockIdx.x;
    const int b = t / 144;
    const int q0 = (t % 144) * 16;
    const int lane = threadIdx.x, r = lane & 15, cg = lane >> 4;
    const f32x4 zero4 = {0.f, 0.f, 0.f, 0.f};
    // ---- out-proj + residual: xt[jt][ri] = row q0+4cg+ri, col jt*16+r
    const ushort_t* arow = obf + ((size_t)b * HW + q0 + r) * 64;
    bf16x8 alo = *(const bf16x8*)(arow + 8 * cg);
    bf16x8 ahi = *(const bf16x8*)(arow + 32 + 8 * cg);
    float xt[4][4];
    #pragma unroll
    for (int jt = 0; jt < 4; ++jt) {
        bf16x8 bl = *(const bf16x8*)(w_outT + (jt * 16 + r) * 64 + 8 * cg);
        bf16x8 bh_ = *(const bf16x8*)(w_outT + (jt * 16 + r) * 64 + 32 + 8 * cg);
        f32x4 acc = zero4;
        acc = MFMA(alo, bl, acc);
        acc = MFMA(ahi, bh_, acc);
        const int c = jt * 16 + r;
        const float bo = b_out[c];
        float4 xr = *(const float4*)(x + (size_t)b * CH * HW + (size_t)c * HW + q0 + 4 * cg);
        xt[jt][0] = acc[0] + bo + xr.x;
        xt[jt][1] = acc[1] + bo + xr.y;
        xt[jt][2] = acc[2] + bo + xr.z;
        xt[jt][3] = acc[3] + bo + xr.w;
    }
    // ---- LN2 row stats: reduce over the 16 r-lanes (each holds 4 cols/row)
    float mr[4], rv[4];
    #pragma unroll
    for (int ri = 0; ri < 4; ++ri) {
        float s  = xt[0][ri] + xt[1][ri] + xt[2][ri] + xt[3][ri];
        float sq = xt[0][ri] * xt[0][ri] + xt[1][ri] * xt[1][ri]
                 + xt[2][ri] * xt[2][ri] + xt[3][ri] * xt[3][ri];
        s  += __shfl_xor(s, 1);  s  += __shfl_xor(s, 2);
        s  += __shfl_xor(s, 4);  s  += __shfl_xor(s, 8);
        sq += __shfl_xor(sq, 1); sq += __shfl_xor(sq, 2);
        sq += __shfl_xor(sq, 4); sq += __shfl_xor(sq, 8);
        mr[ri] = s * (1.f / 64.f);
        rv[ri] = rsqrtf(sq * (1.f / 64.f) - mr[ri] * mr[ri] + 1e-5f);
    }
    // ---- normalize -> LDS [row][ch] bf16
    #pragma unroll
    for (int jt = 0; jt < 4; ++jt) {
        const int c = jt * 16 + r;
        const float gg = g2[c], bb = bt2[c];
        #pragma unroll
        for (int ri = 0; ri < 4; ++ri) {
            const float val = (xt[jt][ri] - mr[ri]) * rv[ri] * gg + bb;
            xn[(4 * cg + ri) * 72 + c] = f2bf(val);
        }
    }
    bf16x8 axlo = *(const bf16x8*)&xn[r * 72 + 8 * cg];
    bf16x8 axhi = *(const bf16x8*)&xn[r * 72 + 32 + 8 * cg];
    // ---- MLP1 + LeakyReLU -> LDS [row][ch] bf16
    #pragma unroll 4
    for (int jt = 0; jt < 16; ++jt) {
        bf16x8 bl = *(const bf16x8*)(wT1 + (jt * 16 + r) * 64 + 8 * cg);
        bf16x8 bh_ = *(const bf16x8*)(wT1 + (jt * 16 + r) * 64 + 32 + 8 * cg);
        f32x4 acc = zero4;
        acc = MFMA(axlo, bl, acc);
        acc = MFMA(axhi, bh_, acc);
        const int c = jt * 16 + r;
        const float bias = b1[c];
        #pragma unroll
        for (int ri = 0; ri < 4; ++ri) {
            float vv = acc[ri] + bias;
            vv = fmaxf(vv, 0.01f * vv);
            hh[(4 * cg + ri) * 264 + c] = f2bf(vv);
        }
    }
    bf16x8 ha[8];
    #pragma unroll
    for (int kw = 0; kw < 8; ++kw)
        ha[kw] = *(const bf16x8*)&hh[r * 264 + kw * 32 + 8 * cg];
    // ---- MLP2 + register-local residual + transposed store
    #pragma unroll
    for (int jt = 0; jt < 4; ++jt) {
        f32x4 acc = zero4;
        #pragma unroll
        for (int kw = 0; kw < 8; ++kw) {
            bf16x8 bf_ = *(const bf16x8*)(wT2 + (jt * 16 + r) * 256 + kw * 32 + 8 * cg);
            acc = MFMA(ha[kw], bf_, acc);
        }
        const int c = jt * 16 + r;
        const float bias = b2[c];
        float4 res;
        res.x = acc[0] + bias + xt[jt][0];
        res.y = acc[1] + bias + xt[jt][1];
        res.z = acc[2] + bias + xt[jt][2];
        res.w = acc[3] + bias + xt[jt][3];
        *(float4*)(out + (size_t)b * CH * HW + (size_t)c * HW + q0 + 4 * cg) = res;
    }
}

extern "C" void kernel_launch(void* const* d_in, const int* in_sizes, int n_in,
                              void* d_out, int out_size, void* d_ws, size_t ws_size,
                              hipStream_t stream)
{
    (void)in_sizes; (void)n_in; (void)out_size; (void)ws_size;
    const float* x     = (const float*)d_in[0];
    const float* y     = (const float*)d_in[1];
    const float* ln1_g = (const float*)d_in[2];
    const float* ln1_b = (const float*)d_in[3];
    const float* w_sa1 = (const float*)d_in[4];
    const float* w_sa2 = (const float*)d_in[5];
    const float* w_se1 = (const float*)d_in[6];
    const float* w_se2 = (const float*)d_in[7];
    const float* w_out = (const float*)d_in[8];
    const float* b_out = (const float*)d_in[9];
    const float* ln2_g = (const float*)d_in[10];
    const float* ln2_b = (const float*)d_in[11];
    const float* w1    = (const float*)d_in[12];
    const float* b1    = (const float*)d_in[13];
    const float* w2    = (const float*)d_in[14];
    const float* b2    = (const float*)d_in[15];
    float* out = (float*)d_out;

    const size_t NP = 8ull * HW * 16;              // 294912
    float* p = (float*)d_ws;
    float* y1f  = p;  p += NP;
    float* sacc = p;  p += 2048;
    ushort_t* u = (ushort_t*)p;
    ushort_t* qbf   = u;  u += NP;
    ushort_t* kbf   = u;  u += NP;
    ushort_t* vtbf  = u;  u += NP;
    ushort_t* obf   = u;  u += NP;
    ushort_t* wsa1T = u;  u += 4096;
    ushort_t* wsa2T = u;  u += 4096;
    ushort_t* wse1T = u;  u += 4096;
    ushort_t* wse2T = u;  u += 4096;
    ushort_t* w_outT= u;  u += 4096;
    ushort_t* wT1   = u;  u += 16384;
    ushort_t* wT2   = u;  u += 16384;
    // total ~3.6 MB of d_ws

    k_wconv<<<208, 256, 0, stream>>>(w_sa1, w_sa2, w_se1, w_se2, w_out, w1, w2,
                                     wsa1T, wsa2T, wse1T, wse2T, w_outT, wT1, wT2,
                                     sacc);
    k_ln_proj<<<576, 64, 0, stream>>>(x, y, ln1_g, ln1_b,
                                      wsa1T, wsa2T, wse1T, wse2T,
                                      y1f, qbf, kbf, vtbf, sacc);
    k_attn<<<dim3(144, 8), 256, 0, stream>>>(qbf, kbf, vtbf, y1f, sacc, obf);
    k_tail<<<288, 64, 0, stream>>>(obf, x, w_outT, b_out, ln2_g, ln2_b,
                                   wT1, b1, wT2, b2, out);
}

// Round 8
// 119.292 us; speedup vs baseline: 2.0598x; 1.0640x over previous
//
#include <hip/hip_runtime.h>

#define HW 2304          // n = 48*48
#define CH 64            // DIM
typedef unsigned short ushort_t;
typedef __attribute__((ext_vector_type(8))) short bf16x8;
typedef __attribute__((ext_vector_type(4))) float f32x4;

#define QSCL (0.25f * 1.44269504088896340736f)   // attn scale * log2(e), folded into Qbf
#define SECM_SCL (0.25f / 144.f)
#define MFMA(a, b, c) __builtin_amdgcn_mfma_f32_16x16x32_bf16((a), (b), (c), 0, 0, 0)

static __device__ __forceinline__ ushort_t f2bf(float f) {
    union { float f; unsigned u; } v; v.f = f;
    unsigned r = v.u + 0x7FFFu + ((v.u >> 16) & 1u);   // RNE
    return (ushort_t)(r >> 16);
}
static __device__ __forceinline__ unsigned cvtpk(float a, float b) {  // lo=a, hi=b
    unsigned r;
    asm("v_cvt_pk_bf16_f32 %0, %1, %2" : "=v"(r) : "v"(a), "v"(b));
    return r;
}
union U8 { unsigned u[4]; bf16x8 v; };

// ---------------------------------------------------------------------------
// K0: weights -> bf16 [out][in]; blocks 0..7 also zero sacc.
// ---------------------------------------------------------------------------
__global__ __launch_bounds__(256) void k_wconv(
    const float* __restrict__ wsa1, const float* __restrict__ wsa2,
    const float* __restrict__ wse1, const float* __restrict__ wse2,
    const float* __restrict__ w_out, const float* __restrict__ w1,
    const float* __restrict__ w2,
    ushort_t* __restrict__ wsa1T, ushort_t* __restrict__ wsa2T,
    ushort_t* __restrict__ wse1T, ushort_t* __restrict__ wse2T,
    ushort_t* __restrict__ w_outT, ushort_t* __restrict__ wT1, ushort_t* __restrict__ wT2,
    float* __restrict__ sacc)
{
    const int blk = blockIdx.x, tid = threadIdx.x;
    if (blk < 8) sacc[blk * 256 + tid] = 0.f;
    if (blk < 80) {                       // five 64x64 transposes
        const int mi = blk >> 4;
        const float* s = mi == 0 ? wsa1 : mi == 1 ? wsa2 : mi == 2 ? wse1 : mi == 3 ? wse2 : w_out;
        ushort_t* d = mi == 0 ? wsa1T : mi == 1 ? wsa2T : mi == 2 ? wse1T : mi == 3 ? wse2T : w_outT;
        const int o = (blk & 15) * 256 + tid;
        d[o] = f2bf(s[(o & 63) * 64 + (o >> 6)]);
    } else if (blk < 144) {               // wT1[j][c] = w1[c][j]
        const int o = (blk - 80) * 256 + tid;
        wT1[o] = f2bf(w1[(o & 63) * 256 + (o >> 6)]);
    } else {                              // wT2[j][c] = w2[c][j]
        const int o = (blk - 144) * 256 + tid;
        wT2[o] = f2bf(w2[(o & 255) * 64 + (o >> 8)]);
    }
}

// ---------------------------------------------------------------------------
// K1: LN + dual projection via MFMA. jt (head) split across blockIdx.y for
// 4x wave parallelism (LN recomputed per head; inputs L2-served).
// grid (576, 4) x 64 (1 wave / 16 rows / 1 head).
// ---------------------------------------------------------------------------
__global__ __launch_bounds__(64) void k_ln_proj(
    const float* __restrict__ x, const float* __restrict__ y,
    const float* __restrict__ g, const float* __restrict__ bb,
    const ushort_t* __restrict__ wsa1T, const ushort_t* __restrict__ wsa2T,
    const ushort_t* __restrict__ wse1T, const ushort_t* __restrict__ wse2T,
    float* __restrict__ y1f, ushort_t* __restrict__ qbf, ushort_t* __restrict__ kbf,
    ushort_t* __restrict__ vtbf, float* __restrict__ sacc)
{
    __shared__ ushort_t ldsA[16 * 24 + 32];   // x1^T tile [d][row], 48B stride
    __shared__ ushort_t ldsB[16 * 24 + 32];   // x2^T tile
    const int task = blockIdx.x;
    const int jt = blockIdx.y;
    const int rt = task % 144;
    const int b  = (task / 144) & 1;
    const int branch = task / 288;
    const int lane = threadIdx.x;
    const int r = lane & 15, cg = lane >> 4;
    const int q0 = rt * 16;
    const float* in = (branch ? y : x) + (size_t)b * CH * HW + q0 + r;
    float lo[8], hi[8];
    float s = 0.f, sq = 0.f;
    #pragma unroll
    for (int ki = 0; ki < 8; ++ki) {
        lo[ki] = in[(size_t)(8 * cg + ki) * HW];
        hi[ki] = in[(size_t)(32 + 8 * cg + ki) * HW];
        s += lo[ki] + hi[ki];
        sq += lo[ki] * lo[ki] + hi[ki] * hi[ki];
    }
    s  += __shfl_xor(s, 16);  s  += __shfl_xor(s, 32);
    sq += __shfl_xor(sq, 16); sq += __shfl_xor(sq, 32);
    const float m  = s * (1.f / 64.f);
    const float rs = rsqrtf(sq * (1.f / 64.f) - m * m + 1e-5f);
    float ga[16], be[16];
    {
        const float4* gp = (const float4*)g;
        const float4* bp = (const float4*)bb;
        *(float4*)&ga[0]  = gp[2 * cg];     *(float4*)&ga[4]  = gp[2 * cg + 1];
        *(float4*)&ga[8]  = gp[8 + 2 * cg]; *(float4*)&ga[12] = gp[9 + 2 * cg];
        *(float4*)&be[0]  = bp[2 * cg];     *(float4*)&be[4]  = bp[2 * cg + 1];
        *(float4*)&be[8]  = bp[8 + 2 * cg]; *(float4*)&be[12] = bp[9 + 2 * cg];
    }
    float nlo[8], nhi[8];
    #pragma unroll
    for (int ki = 0; ki < 8; ++ki) {
        nlo[ki] = (lo[ki] - m) * rs * ga[ki]     + be[ki];
        nhi[ki] = (hi[ki] - m) * rs * ga[8 + ki] + be[8 + ki];
    }
    U8 alo, ahi;
    #pragma unroll
    for (int p = 0; p < 4; ++p) {
        alo.u[p] = cvtpk(nlo[2 * p], nlo[2 * p + 1]);
        ahi.u[p] = cvtpk(nhi[2 * p], nhi[2 * p + 1]);
    }
    const ushort_t* wp1 = branch ? wsa1T : wse1T;
    const ushort_t* wp2 = branch ? wsa2T : wse2T;
    const f32x4 zero4 = {0.f, 0.f, 0.f, 0.f};
    const int bh = b * 4 + jt;
    bf16x8 bl1 = *(const bf16x8*)(wp1 + (jt * 16 + r) * 64 + 8 * cg);
    bf16x8 bh1 = *(const bf16x8*)(wp1 + (jt * 16 + r) * 64 + 32 + 8 * cg);
    f32x4 acc1 = zero4;
    acc1 = MFMA(alo.v, bl1, acc1);
    acc1 = MFMA(ahi.v, bh1, acc1);
    bf16x8 bl2 = *(const bf16x8*)(wp2 + (jt * 16 + r) * 64 + 8 * cg);
    bf16x8 bh2 = *(const bf16x8*)(wp2 + (jt * 16 + r) * 64 + 32 + 8 * cg);
    f32x4 acc2 = zero4;
    acc2 = MFMA(alo.v, bl2, acc2);
    acc2 = MFMA(ahi.v, bh2, acc2);
    if (branch == 0) {
        // x1 -> V^T bf16 global; x1,x2 -> per-wave LDS [d][row] tiles
        uint2 pk1; pk1.x = cvtpk(acc1[0], acc1[1]); pk1.y = cvtpk(acc1[2], acc1[3]);
        *(uint2*)(vtbf + (size_t)(bh * 16 + r) * HW + q0 + 4 * cg) = pk1;
        *(uint2*)&ldsA[r * 24 + 4 * cg] = pk1;
        uint2 pk2; pk2.x = cvtpk(acc2[0], acc2[1]); pk2.y = cvtpk(acc2[2], acc2[3]);
        *(uint2*)&ldsB[r * 24 + 4 * cg] = pk2;
        bf16x8 af = {0, 0, 0, 0, 0, 0, 0, 0};
        bf16x8 bf_ = {0, 0, 0, 0, 0, 0, 0, 0};
        if (cg < 2) {
            af  = *(const bf16x8*)&ldsA[r * 24 + 8 * cg];
            bf_ = *(const bf16x8*)&ldsB[r * 24 + 8 * cg];
        }
        f32x4 sp = MFMA(af, bf_, zero4);
        #pragma unroll
        for (int ri = 0; ri < 4; ++ri)
            atomicAdd(&sacc[bh * 256 + (4 * cg + ri) * 16 + r], sp[ri]);
    } else {
        #pragma unroll
        for (int ri = 0; ri < 4; ++ri) {
            const int q = q0 + 4 * cg + ri;
            y1f[((size_t)bh * HW + q) * 16 + r] = acc1[ri];
            qbf[((size_t)bh * HW + q) * 16 + r] = f2bf(acc1[ri] * QSCL);
            kbf[((size_t)bh * HW + q) * 16 + r] = f2bf(acc2[ri]);
        }
    }
}

// ---------------------------------------------------------------------------
// K2: barrier-free MFMA attention, 8-way k-split (512 thr) for 2x occupancy.
// grid (144, 8) x 512. Prologue: channel softmax from sacc.
// ---------------------------------------------------------------------------
__global__ __launch_bounds__(512) void k_attn(
    const ushort_t* __restrict__ qbf, const ushort_t* __restrict__ kbf,
    const ushort_t* __restrict__ vtbf, const float* __restrict__ y1f,
    const float* __restrict__ sacc, ushort_t* __restrict__ obf)
{
    __shared__ uint4 pbuf4[8][80];          // per-wave P^T tile: 16 q x 80B
    __shared__ f32x4 cacc[8][64];
    __shared__ float clsum[8][64];
    __shared__ float sraw[256];
    __shared__ float smv[256];
    const int qt = blockIdx.x, bh = blockIdx.y;
    const int tid = threadIdx.x;
    const int w = tid >> 6, lane = tid & 63;
    const int q16 = lane & 15, g = lane >> 4;
    const int q0 = qt * 16;
    if (tid < 256) sraw[tid] = sacc[bh * 256 + tid] * SECM_SCL;
    __syncthreads();
    if (tid < 256) {
        const int i = tid >> 4;
        float mx = -1e30f;
        #pragma unroll
        for (int jj = 0; jj < 16; ++jj) mx = fmaxf(mx, sraw[i * 16 + jj]);
        float sum = 0.f;
        #pragma unroll
        for (int jj = 0; jj < 16; ++jj) sum += __expf(sraw[i * 16 + jj] - mx);
        smv[tid] = __expf(sraw[tid] - mx) / sum;   // consumed after post-loop barrier
    }

    bf16x8 qfrag = {0, 0, 0, 0, 0, 0, 0, 0};
    if (g < 2) qfrag = *(const bf16x8*)(qbf + ((size_t)bh * HW + q0 + q16) * 16 + g * 8);

    unsigned char* pw = (unsigned char*)&pbuf4[w][0];
    const ushort_t* kbase = kbf + (size_t)bh * HW * 16;
    const ushort_t* vbase = vtbf + (size_t)(bh * 16 + q16) * HW;
    f32x4 oacc = {0.f, 0.f, 0.f, 0.f};
    float lsum = 0.f;
    const f32x4 zero4 = {0.f, 0.f, 0.f, 0.f};

    #pragma unroll 3
    for (int wi = 0; wi < 9; ++wi) {
        const int k0 = w * 288 + wi * 32;
        bf16x8 kf0 = *(const bf16x8*)(kbase + (size_t)(k0 + q16) * 16 + (g & 1) * 8);
        bf16x8 kf1 = *(const bf16x8*)(kbase + (size_t)(k0 + 16 + q16) * 16 + (g & 1) * 8);
        f32x4 s0 = MFMA(kf0, qfrag, zero4);
        f32x4 s1 = MFMA(kf1, qfrag, zero4);
        const float e00 = exp2f(s0[0]), e01 = exp2f(s0[1]), e02 = exp2f(s0[2]), e03 = exp2f(s0[3]);
        const float e10 = exp2f(s1[0]), e11 = exp2f(s1[1]), e12 = exp2f(s1[2]), e13 = exp2f(s1[3]);
        lsum += ((e00 + e01) + (e02 + e03)) + ((e10 + e11) + (e12 + e13));
        *(unsigned*)(pw + q16 * 80 + 8 * g)      = cvtpk(e00, e01);
        *(unsigned*)(pw + q16 * 80 + 8 * g + 4)  = cvtpk(e02, e03);
        *(unsigned*)(pw + q16 * 80 + 32 + 8 * g) = cvtpk(e10, e11);
        *(unsigned*)(pw + q16 * 80 + 36 + 8 * g) = cvtpk(e12, e13);
        bf16x8 vfrag = *(const bf16x8*)(vbase + k0 + 8 * g);
        bf16x8 pfrag = *(const bf16x8*)(pw + q16 * 80 + 16 * g);
        oacc = MFMA(vfrag, pfrag, oacc);
    }
    cacc[w][lane] = oacc;
    clsum[w][lane] = lsum;
    __syncthreads();
    if (tid < 64) {
        f32x4 t = cacc[0][lane];
        float L = clsum[0][lane];
        #pragma unroll
        for (int ww = 1; ww < 8; ++ww) {
            f32x4 tw = cacc[ww][lane];
            t[0] += tw[0]; t[1] += tw[1]; t[2] += tw[2]; t[3] += tw[3];
            L += clsum[ww][lane];
        }
        L += __shfl_xor(L, 16);
        L += __shfl_xor(L, 32);
        const float invl = 1.f / L;
        const float* yrow = y1f + ((size_t)bh * HW + q0 + q16) * 16;
        float ya[16];
        #pragma unroll
        for (int i = 0; i < 4; ++i) *(float4*)&ya[4 * i] = ((const float4*)yrow)[i];
        float gate[4] = {0.f, 0.f, 0.f, 0.f};
        #pragma unroll
        for (int i = 0; i < 16; ++i) {
            #pragma unroll
            for (int rr = 0; rr < 4; ++rr) gate[rr] += ya[i] * smv[i * 16 + g * 4 + rr];
        }
        const int b = bh >> 2, h = bh & 3;
        float r0 = t[0] * invl * gate[0];
        float r1 = t[1] * invl * gate[1];
        float r2 = t[2] * invl * gate[2];
        float r3 = t[3] * invl * gate[3];
        uint2 pk; pk.x = cvtpk(r0, r1); pk.y = cvtpk(r2, r3);
        *(uint2*)(obf + ((size_t)b * HW + q0 + q16) * 64 + h * 16 + g * 4) = pk;
    }
}

// ---------------------------------------------------------------------------
// K3: fused tail, 4 cooperating waves per 16-row tile (grid 288 x 256).
// Phase A: wave w -> outproj jt=w -> xtile f32 LDS. Phase B: mlp1 jt=4w..4w+3
// -> hh bf16 LDS. Phase C: mlp2 jt=w + residual + transposed store.
// ---------------------------------------------------------------------------
__global__ __launch_bounds__(256) void k_tail(
    const ushort_t* __restrict__ obf, const float* __restrict__ x,
    const ushort_t* __restrict__ w_outT, const float* __restrict__ b_out,
    const float* __restrict__ g2, const float* __restrict__ bt2,
    const ushort_t* __restrict__ wT1, const float* __restrict__ b1,
    const ushort_t* __restrict__ wT2, const float* __restrict__ b2,
    float* __restrict__ out)
{
    __shared__ float xtile[16][68];          // post-residual tile [row][ch]
    __shared__ ushort_t hh[16 * 264 + 16];   // hidden [row][ch], 528B stride
    const int t = blockIdx.x;
    const int b = t / 144;
    const int q0 = (t % 144) * 16;
    const int tid = threadIdx.x;
    const int w = tid >> 6, lane = tid & 63;
    const int r = lane & 15, cg = lane >> 4;
    const f32x4 zero4 = {0.f, 0.f, 0.f, 0.f};
    // ---- phase A: out-proj + residual, wave w handles jt = w
    const ushort_t* arow = obf + ((size_t)b * HW + q0 + r) * 64;
    bf16x8 alo = *(const bf16x8*)(arow + 8 * cg);
    bf16x8 ahi = *(const bf16x8*)(arow + 32 + 8 * cg);
    {
        bf16x8 bl = *(const bf16x8*)(w_outT + (w * 16 + r) * 64 + 8 * cg);
        bf16x8 bh_ = *(const bf16x8*)(w_outT + (w * 16 + r) * 64 + 32 + 8 * cg);
        f32x4 acc = zero4;
        acc = MFMA(alo, bl, acc);
        acc = MFMA(ahi, bh_, acc);
        const int c = w * 16 + r;
        const float bo = b_out[c];
        float4 xr = *(const float4*)(x + (size_t)b * CH * HW + (size_t)c * HW + q0 + 4 * cg);
        xtile[4 * cg + 0][c] = acc[0] + bo + xr.x;
        xtile[4 * cg + 1][c] = acc[1] + bo + xr.y;
        xtile[4 * cg + 2][c] = acc[2] + bo + xr.z;
        xtile[4 * cg + 3][c] = acc[3] + bo + xr.w;
    }
    __syncthreads();
    // ---- LN2 stats for row r (redundant across waves; LDS-served)
    float s = 0.f, sq = 0.f;
    #pragma unroll
    for (int j = 0; j < 16; ++j) {
        const float v = xtile[r][cg * 16 + j];
        s += v; sq += v * v;
    }
    s  += __shfl_xor(s, 16);  s  += __shfl_xor(s, 32);
    sq += __shfl_xor(sq, 16); sq += __shfl_xor(sq, 32);
    const float m  = s * (1.f / 64.f);
    const float rs = rsqrtf(sq * (1.f / 64.f) - m * m + 1e-5f);
    // ---- A-frags for mlp1: xn[row=r][8cg.. / 32+8cg..]
    float ga[16], be[16];
    {
        const float4* gp = (const float4*)g2;
        const float4* bp = (const float4*)bt2;
        *(float4*)&ga[0]  = gp[2 * cg];     *(float4*)&ga[4]  = gp[2 * cg + 1];
        *(float4*)&ga[8]  = gp[8 + 2 * cg]; *(float4*)&ga[12] = gp[9 + 2 * cg];
        *(float4*)&be[0]  = bp[2 * cg];     *(float4*)&be[4]  = bp[2 * cg + 1];
        *(float4*)&be[8]  = bp[8 + 2 * cg]; *(float4*)&be[12] = bp[9 + 2 * cg];
    }
    float nlo[8], nhi[8];
    #pragma unroll
    for (int ki = 0; ki < 8; ++ki) {
        nlo[ki] = (xtile[r][8 * cg + ki]      - m) * rs * ga[ki]     + be[ki];
        nhi[ki] = (xtile[r][32 + 8 * cg + ki] - m) * rs * ga[8 + ki] + be[8 + ki];
    }
    U8 axlo, axhi;
    #pragma unroll
    for (int p = 0; p < 4; ++p) {
        axlo.u[p] = cvtpk(nlo[2 * p], nlo[2 * p + 1]);
        axhi.u[p] = cvtpk(nhi[2 * p], nhi[2 * p + 1]);
    }
    // ---- phase B: mlp1 + LeakyReLU, wave w handles jt = 4w..4w+3
    #pragma unroll
    for (int jj = 0; jj < 4; ++jj) {
        const int jt = 4 * w + jj;
        bf16x8 bl = *(const bf16x8*)(wT1 + (jt * 16 + r) * 64 + 8 * cg);
        bf16x8 bh_ = *(const bf16x8*)(wT1 + (jt * 16 + r) * 64 + 32 + 8 * cg);
        f32x4 acc = zero4;
        acc = MFMA(axlo.v, bl, acc);
        acc = MFMA(axhi.v, bh_, acc);
        const int c = jt * 16 + r;
        const float bias = b1[c];
        #pragma unroll
        for (int ri = 0; ri < 4; ++ri) {
            float vv = acc[ri] + bias;
            vv = fmaxf(vv, 0.01f * vv);
            hh[(4 * cg + ri) * 264 + c] = f2bf(vv);
        }
    }
    __syncthreads();
    // ---- phase C: mlp2 + residual + transposed store, wave w handles jt = w
    bf16x8 ha[8];
    #pragma unroll
    for (int kw = 0; kw < 8; ++kw)
        ha[kw] = *(const bf16x8*)&hh[r * 264 + kw * 32 + 8 * cg];
    f32x4 acc = zero4;
    #pragma unroll
    for (int kw = 0; kw < 8; ++kw) {
        bf16x8 bf_ = *(const bf16x8*)(wT2 + (w * 16 + r) * 256 + kw * 32 + 8 * cg);
        acc = MFMA(ha[kw], bf_, acc);
    }
    const int c = w * 16 + r;
    const float bias = b2[c];
    float4 res;
    res.x = acc[0] + bias + xtile[4 * cg + 0][c];
    res.y = acc[1] + bias + xtile[4 * cg + 1][c];
    res.z = acc[2] + bias + xtile[4 * cg + 2][c];
    res.w = acc[3] + bias + xtile[4 * cg + 3][c];
    *(float4*)(out + (size_t)b * CH * HW + (size_t)c * HW + q0 + 4 * cg) = res;
}

extern "C" void kernel_launch(void* const* d_in, const int* in_sizes, int n_in,
                              void* d_out, int out_size, void* d_ws, size_t ws_size,
                              hipStream_t stream)
{
    (void)in_sizes; (void)n_in; (void)out_size; (void)ws_size;
    const float* x     = (const float*)d_in[0];
    const float* y     = (const float*)d_in[1];
    const float* ln1_g = (const float*)d_in[2];
    const float* ln1_b = (const float*)d_in[3];
    const float* w_sa1 = (const float*)d_in[4];
    const float* w_sa2 = (const float*)d_in[5];
    const float* w_se1 = (const float*)d_in[6];
    const float* w_se2 = (const float*)d_in[7];
    const float* w_out = (const float*)d_in[8];
    const float* b_out = (const float*)d_in[9];
    const float* ln2_g = (const float*)d_in[10];
    const float* ln2_b = (const float*)d_in[11];
    const float* w1    = (const float*)d_in[12];
    const float* b1    = (const float*)d_in[13];
    const float* w2    = (const float*)d_in[14];
    const float* b2    = (const float*)d_in[15];
    float* out = (float*)d_out;

    const size_t NP = 8ull * HW * 16;              // 294912
    float* p = (float*)d_ws;
    float* y1f  = p;  p += NP;
    float* sacc = p;  p += 2048;
    ushort_t* u = (ushort_t*)p;
    ushort_t* qbf   = u;  u += NP;
    ushort_t* kbf   = u;  u += NP;
    ushort_t* vtbf  = u;  u += NP;
    ushort_t* obf   = u;  u += NP;
    ushort_t* wsa1T = u;  u += 4096;
    ushort_t* wsa2T = u;  u += 4096;
    ushort_t* wse1T = u;  u += 4096;
    ushort_t* wse2T = u;  u += 4096;
    ushort_t* w_outT= u;  u += 4096;
    ushort_t* wT1   = u;  u += 16384;
    ushort_t* wT2   = u;  u += 16384;
    // total ~3.6 MB of d_ws

    k_wconv<<<208, 256, 0, stream>>>(w_sa1, w_sa2, w_se1, w_se2, w_out, w1, w2,
                                     wsa1T, wsa2T, wse1T, wse2T, w_outT, wT1, wT2,
                                     sacc);
    k_ln_proj<<<dim3(576, 4), 64, 0, stream>>>(x, y, ln1_g, ln1_b,
                                               wsa1T, wsa2T, wse1T, wse2T,
                                               y1f, qbf, kbf, vtbf, sacc);
    k_attn<<<dim3(144, 8), 512, 0, stream>>>(qbf, kbf, vtbf, y1f, sacc, obf);
    k_tail<<<288, 256, 0, stream>>>(obf, x, w_outT, b_out, ln2_g, ln2_b,
                                    wT1, b1, wT2, b2, out);
}